// Round 1
// baseline (1226.089 us; speedup 1.0000x reference)
//
#include <hip/hip_runtime.h>
#include <hip/hip_bf16.h>
#include <math.h>

#define L_SEQ 16384
#define DM 256
#define DI 512
#define DS 16
#define NCH 128   // number of scan chunks
#define CHL 128   // chunk length (NCH*CHL == L_SEQ)

__device__ __forceinline__ float warpSum(float v){
#pragma unroll
  for(int o=32;o;o>>=1) v += __shfl_xor(v,o);
  return v;
}
__device__ __forceinline__ float gelu_f(float x){
  float x3 = x*x*x;
  return 0.5f*x*(1.0f + tanhf(0.7978845608028654f*(x + 0.044715f*x3)));
}
__device__ __forceinline__ float silu_f(float x){
  return x / (1.0f + __expf(-x));
}
__device__ __forceinline__ float softplus_f(float x){
  return fmaxf(x,0.0f) + log1pf(__expf(-fabsf(x)));
}

// ---- input projection + LN + gelu: u = gelu(LN(x@Win + bin)) ----
__global__ void k_input(const float* __restrict__ x, const float* __restrict__ Win,
                        const float* __restrict__ bin, const float* __restrict__ g,
                        const float* __restrict__ b, float* __restrict__ u){
  int r = blockIdx.x, t = threadIdx.x;
  __shared__ float xr[32];
  __shared__ float sA[4], sB[4];
  if(t<32) xr[t] = x[r*32+t];
  __syncthreads();
  float v = bin[t];
#pragma unroll
  for(int k=0;k<32;k++) v = fmaf(xr[k], Win[k*DM+t], v);
  float s = warpSum(v), sq = warpSum(v*v);
  if((t&63)==0){ sA[t>>6]=s; sB[t>>6]=sq; }
  __syncthreads();
  float mean = (sA[0]+sA[1]+sA[2]+sA[3])*(1.0f/DM);
  float msq  = (sB[0]+sB[1]+sB[2]+sB[3])*(1.0f/DM);
  float var = msq - mean*mean;
  float nv = (v-mean)*rsqrtf(var+1e-5f)*g[t]+b[t];
  u[r*DM+t] = gelu_f(nv);
}

// ---- rmsnorm over 256 ----
__global__ void k_rms(const float* __restrict__ u, const float* __restrict__ w, float* __restrict__ o){
  int r=blockIdx.x, t=threadIdx.x;
  __shared__ float sA[4];
  float v = u[r*DM+t];
  float sq = warpSum(v*v);
  if((t&63)==0) sA[t>>6]=sq;
  __syncthreads();
  float ms = (sA[0]+sA[1]+sA[2]+sA[3])*(1.0f/DM);
  o[r*DM+t] = v*rsqrtf(ms+1e-5f)*w[t];
}

// ---- layernorm over 256 ----
__global__ void k_ln(const float* __restrict__ u, const float* __restrict__ g,
                     const float* __restrict__ b, float* __restrict__ o){
  int r=blockIdx.x, t=threadIdx.x;
  __shared__ float sA[4], sB[4];
  float v = u[r*DM+t];
  float s = warpSum(v), sq = warpSum(v*v);
  if((t&63)==0){ sA[t>>6]=s; sB[t>>6]=sq; }
  __syncthreads();
  float mean = (sA[0]+sA[1]+sA[2]+sA[3])*(1.0f/DM);
  float msq  = (sB[0]+sB[1]+sB[2]+sB[3])*(1.0f/DM);
  float var = msq - mean*mean;
  o[r*DM+t] = (v-mean)*rsqrtf(var+1e-5f)*g[t]+b[t];
}

// ---- tiled fp32 GEMM: C[M,N] = A[M,K] @ W[K,N], EPI: 0=store,1=+R,2=gelu(+bias) ----
template<int EPI>
__global__ __launch_bounds__(256) void k_gemm(const float* __restrict__ A, const float* __restrict__ W,
                       const float* __restrict__ bias, const float* __restrict__ R,
                       float* __restrict__ C, int M, int K, int N){
  const int BM=128, BN=64, BK=16;
  __shared__ float As[BK][BM+4];
  __shared__ float Bs[BK][BN+4];
  int t = threadIdx.x;
  int tx = t&15, ty = t>>4;
  int m0 = blockIdx.y*BM, n0 = blockIdx.x*BN;
  float acc[8][4] = {};
  int arow = t>>1, ak = (t&1)*8;
  int brow = t>>4, bcol = (t&15)*4;
  for(int kt=0; kt<K; kt+=BK){
    float4 a0 = *(const float4*)&A[(m0+arow)*K + kt + ak];
    float4 a1 = *(const float4*)&A[(m0+arow)*K + kt + ak + 4];
    float4 bv = *(const float4*)&W[(kt+brow)*N + n0 + bcol];
    __syncthreads();
    As[ak+0][arow]=a0.x; As[ak+1][arow]=a0.y; As[ak+2][arow]=a0.z; As[ak+3][arow]=a0.w;
    As[ak+4][arow]=a1.x; As[ak+5][arow]=a1.y; As[ak+6][arow]=a1.z; As[ak+7][arow]=a1.w;
    *(float4*)&Bs[brow][bcol] = bv;
    __syncthreads();
#pragma unroll
    for(int k=0;k<BK;k++){
      float4 va0 = *(const float4*)&As[k][ty*8];
      float4 va1 = *(const float4*)&As[k][ty*8+4];
      float4 vb  = *(const float4*)&Bs[k][tx*4];
      float av[8] = {va0.x,va0.y,va0.z,va0.w,va1.x,va1.y,va1.z,va1.w};
      float bw[4] = {vb.x,vb.y,vb.z,vb.w};
#pragma unroll
      for(int i=0;i<8;i++)
#pragma unroll
        for(int j=0;j<4;j++)
          acc[i][j] = fmaf(av[i], bw[j], acc[i][j]);
    }
  }
#pragma unroll
  for(int i=0;i<8;i++){
    int row = m0 + ty*8 + i;
    int col = n0 + tx*4;
    float4 o;
    if(EPI==2){
      o.x = gelu_f(acc[i][0]+bias[col+0]);
      o.y = gelu_f(acc[i][1]+bias[col+1]);
      o.z = gelu_f(acc[i][2]+bias[col+2]);
      o.w = gelu_f(acc[i][3]+bias[col+3]);
    } else if(EPI==1){
      float4 rv = *(const float4*)&R[row*N+col];
      o.x = acc[i][0]+rv.x; o.y = acc[i][1]+rv.y;
      o.z = acc[i][2]+rv.z; o.w = acc[i][3]+rv.w;
    } else {
      o.x = acc[i][0]; o.y = acc[i][1]; o.z = acc[i][2]; o.w = acc[i][3];
    }
    *(float4*)&C[row*N+col] = o;
  }
}

// ---- causal depthwise conv (k=4) + bias + silu; xin = xz[:, :512] ----
__global__ void k_conv(const float* __restrict__ xz, const float* __restrict__ cw,
                       const float* __restrict__ cb, float* __restrict__ xs){
  int idx = blockIdx.x*blockDim.x + threadIdx.x; // L_SEQ*128 threads
  int l = idx>>7, c4 = (idx&127)*4;
  float acc[4];
#pragma unroll
  for(int j=0;j<4;j++) acc[j] = cb[c4+j];
#pragma unroll
  for(int k=0;k<4;k++){
    int ls = l-3+k;
    if(ls>=0){
      float4 xv = *(const float4*)&xz[ls*1024 + c4];
      acc[0] = fmaf(xv.x, cw[(c4+0)*4+k], acc[0]);
      acc[1] = fmaf(xv.y, cw[(c4+1)*4+k], acc[1]);
      acc[2] = fmaf(xv.z, cw[(c4+2)*4+k], acc[2]);
      acc[3] = fmaf(xv.w, cw[(c4+3)*4+k], acc[3]);
    }
  }
  float4 o = {silu_f(acc[0]),silu_f(acc[1]),silu_f(acc[2]),silu_f(acc[3])};
  *(float4*)&xs[l*DI + c4] = o;
}

// ---- dbc = xs @ xpW  (K=512, N=48), 16 rows per block ----
__global__ __launch_bounds__(256) void k_xproj(const float* __restrict__ xs,
                        const float* __restrict__ xpW, float* __restrict__ dbc){
  __shared__ float xsl[16][514];
  int t = threadIdx.x;
  int r0 = blockIdx.x*16;
#pragma unroll
  for(int i=0;i<32;i++){
    int idx = t + i*256;
    xsl[idx>>9][idx&511] = xs[(r0 + (idx>>9))*DI + (idx&511)];
  }
  __syncthreads();
  int row = t&15, cg = t>>4;
  float w0=0,w1=0,w2=0;
  for(int k=0;k<DI;k++){
    float xv = xsl[row][k];
    const float* wp = &xpW[k*48 + cg*3];
    w0 = fmaf(xv, wp[0], w0);
    w1 = fmaf(xv, wp[1], w1);
    w2 = fmaf(xv, wp[2], w2);
  }
  float* o = &dbc[(r0+row)*48 + cg*3];
  o[0]=w0; o[1]=w1; o[2]=w2;
}

// ---- delta = softplus(dbc[:, :16] @ dtW + dtB) ----
__global__ void k_delta(const float* __restrict__ dbc, const float* __restrict__ dtW,
                        const float* __restrict__ dtB, float* __restrict__ delta){
  int l = blockIdx.x>>1;
  int e = threadIdx.x + (blockIdx.x&1)*256;
  float s = dtB[e];
#pragma unroll
  for(int k=0;k<16;k++) s = fmaf(dbc[l*48+k], dtW[k*DI+e], s);
  delta[l*DI+e] = softplus_f(s);
}

// ---- scan phase 1: per-chunk totals (prod dA, local carry) ----
__global__ __launch_bounds__(256) void k_scan1(const float* __restrict__ delta, const float* __restrict__ xs,
                        const float* __restrict__ dbc, const float* __restrict__ A_log,
                        float* __restrict__ Atot, float* __restrict__ Btot){
  int t = threadIdx.x;
  int n = t&15, es = t>>4;
  int e = blockIdx.x*16 + es;
  int chunk = blockIdx.y;
  float A = -__expf(A_log[e*DS+n]);
  float carry = 0.f, aprod = 1.f;
  int l0 = chunk*CHL;
#pragma unroll 4
  for(int l=l0; l<l0+CHL; l++){
    float d  = delta[l*DI+e];
    float xv = xs[l*DI+e];
    float bv = dbc[l*48+16+n];
    float dA = __expf(d*A);
    carry = fmaf(carry, dA, d*xv*bv);
    aprod *= dA;
  }
  int o = chunk*8192 + blockIdx.x*256 + t;
  Atot[o] = aprod; Btot[o] = carry;
}

// ---- scan phase 2: carry-in per chunk ----
__global__ void k_scan2(const float* __restrict__ Atot, const float* __restrict__ Btot,
                        float* __restrict__ h0){
  int tg = blockIdx.x*256 + threadIdx.x;
  float carry = 0.f;
#pragma unroll 4
  for(int c=0;c<NCH;c++){
    h0[c*8192+tg] = carry;
    carry = fmaf(carry, Atot[c*8192+tg], Btot[c*8192+tg]);
  }
}

// ---- scan phase 3: replay with carry-in, fuse y = sum_n h*C + xs*D ----
__global__ __launch_bounds__(256) void k_scan3(const float* __restrict__ delta, const float* __restrict__ xs,
                        const float* __restrict__ dbc, const float* __restrict__ A_log,
                        const float* __restrict__ Dp, const float* __restrict__ h0,
                        float* __restrict__ y){
  int t = threadIdx.x;
  int n = t&15, es = t>>4;
  int e = blockIdx.x*16 + es;
  int chunk = blockIdx.y;
  float A = -__expf(A_log[e*DS+n]);
  float carry = h0[chunk*8192 + blockIdx.x*256 + t];
  float Dv = Dp[e];
  int l0 = chunk*CHL;
#pragma unroll 2
  for(int l=l0; l<l0+CHL; l++){
    float d  = delta[l*DI+e];
    float xv = xs[l*DI+e];
    float bv = dbc[l*48+16+n];
    float cv = dbc[l*48+32+n];
    float dA = __expf(d*A);
    carry = fmaf(carry, dA, d*xv*bv);
    float p = carry*cv;
    p += __shfl_xor(p,1); p += __shfl_xor(p,2);
    p += __shfl_xor(p,4); p += __shfl_xor(p,8);
    if(n==0) y[l*DI+e] = fmaf(xv, Dv, p);
  }
}

// ---- g = y * silu(z) (in place on y) ----
__global__ void k_ymul(float* __restrict__ y, const float* __restrict__ xz){
  int idx = blockIdx.x*blockDim.x + threadIdx.x;
  int l = idx>>9, c = idx&511;
  y[idx] = y[idx]*silu_f(xz[l*1024+512+c]);
}

// ---- final: LN(128) -> @W2(128,1)+b2 -> tanh, one wave per row ----
__global__ void k_final(const float* __restrict__ h2, const float* __restrict__ g,
                        const float* __restrict__ b, const float* __restrict__ W2,
                        const float* __restrict__ b2, float* __restrict__ out){
  int lane = threadIdx.x&63;
  int wv = threadIdx.x>>6;
  int r = blockIdx.x*4 + wv;
  float v0 = h2[r*128+lane], v1 = h2[r*128+64+lane];
  float s = v0+v1, sq = v0*v0+v1*v1;
#pragma unroll
  for(int o=32;o;o>>=1){ s += __shfl_xor(s,o); sq += __shfl_xor(sq,o); }
  float mean = s*(1.0f/128), var = sq*(1.0f/128) - mean*mean;
  float rs = rsqrtf(var+1e-5f);
  float n0 = (v0-mean)*rs*g[lane]+b[lane];
  float n1 = (v1-mean)*rs*g[lane+64]+b[lane+64];
  float d = n0*W2[lane] + n1*W2[lane+64];
#pragma unroll
  for(int o=32;o;o>>=1) d += __shfl_xor(d,o);
  if(lane==0) out[r] = tanhf(d + b2[0]);
}

extern "C" void kernel_launch(void* const* d_in, const int* in_sizes, int n_in,
                              void* d_out, int out_size, void* d_ws, size_t ws_size,
                              hipStream_t stream){
  const float* x    = (const float*)d_in[0];
  const float* Win  = (const float*)d_in[1];
  const float* bin  = (const float*)d_in[2];
  const float* ln1g = (const float*)d_in[3];
  const float* ln1b = (const float*)d_in[4];
  const float* rmsw = (const float*)d_in[5];
  const float* inW  = (const float*)d_in[6];
  const float* convW= (const float*)d_in[7];
  const float* convB= (const float*)d_in[8];
  const float* xpW  = (const float*)d_in[9];
  const float* dtW  = (const float*)d_in[10];
  const float* dtB  = (const float*)d_in[11];
  const float* A_log= (const float*)d_in[12];
  const float* Dp   = (const float*)d_in[13];
  const float* outW = (const float*)d_in[14];
  const float* ln2g = (const float*)d_in[15];
  const float* ln2b = (const float*)d_in[16];
  const float* W1   = (const float*)d_in[17];
  const float* b1   = (const float*)d_in[18];
  const float* ln3g = (const float*)d_in[19];
  const float* ln3b = (const float*)d_in[20];
  const float* W2   = (const float*)d_in[21];
  const float* b2   = (const float*)d_in[22];
  float* out = (float*)d_out;
  float* ws = (float*)d_ws;
  float* u    = ws;                    // 16384*256
  float* hn   = ws + 4194304;          // 16384*256
  float* xz   = ws + 8388608;          // 16384*1024
  float* xs   = ws + 25165824;         // 16384*512
  float* dbc  = ws + 33554432;         // 16384*48
  float* delta= ws + 34340864;         // 16384*512
  float* y    = ws + 42729472;         // 16384*512
  float* Atot = ws + 51118080;         // 128*8192
  float* Btot = ws + 52166656;         // 128*8192
  float* h0   = ws + 53215232;         // 128*8192
  float* h2   = ws + 54263808;         // 16384*128

  k_input<<<L_SEQ,256,0,stream>>>(x,Win,bin,ln1g,ln1b,u);
  for(int i=0;i<2;i++){
    k_rms<<<L_SEQ,256,0,stream>>>(u, rmsw+i*DM, hn);
    k_gemm<0><<<dim3(1024/64, L_SEQ/128),256,0,stream>>>(hn, inW+i*DM*1024, nullptr, nullptr, xz, L_SEQ, DM, 1024);
    k_conv<<<L_SEQ*128/256,256,0,stream>>>(xz, convW+i*DI*4, convB+i*DI, xs);
    k_xproj<<<L_SEQ/16,256,0,stream>>>(xs, xpW+i*DI*48, dbc);
    k_delta<<<L_SEQ*2,256,0,stream>>>(dbc, dtW+i*16*DI, dtB+i*DI, delta);
    k_scan1<<<dim3(32,NCH),256,0,stream>>>(delta, xs, dbc, A_log+i*DI*DS, Atot, Btot);
    k_scan2<<<32,256,0,stream>>>(Atot, Btot, h0);
    k_scan3<<<dim3(32,NCH),256,0,stream>>>(delta, xs, dbc, A_log+i*DI*DS, Dp+i*DI, h0, y);
    k_ymul<<<L_SEQ*DI/256,256,0,stream>>>(y, xz);
    k_gemm<1><<<dim3(DM/64, L_SEQ/128),256,0,stream>>>(y, outW+i*DI*DM, nullptr, u, u, L_SEQ, DI, DM);
  }
  k_ln<<<L_SEQ,256,0,stream>>>(u, ln2g, ln2b, hn);
  k_gemm<2><<<dim3(128/64, L_SEQ/128),256,0,stream>>>(hn, W1, b1, nullptr, h2, L_SEQ, DM, 128);
  k_final<<<L_SEQ/4,256,0,stream>>>(h2, ln3g, ln3b, W2, b2, out);
}

// Round 2
// 1004.241 us; speedup vs baseline: 1.2209x; 1.2209x over previous
//
#include <hip/hip_runtime.h>
#include <hip/hip_bf16.h>
#include <math.h>

#define L_SEQ 16384
#define DM 256
#define DI 512
#define DS 16
#define NCH 256   // number of scan chunks
#define CHL 64    // chunk length (NCH*CHL == L_SEQ)

__device__ __forceinline__ float warpSum(float v){
#pragma unroll
  for(int o=32;o;o>>=1) v += __shfl_xor(v,o);
  return v;
}
__device__ __forceinline__ float gelu_f(float x){
  float x3 = x*x*x;
  return 0.5f*x*(1.0f + tanhf(0.7978845608028654f*(x + 0.044715f*x3)));
}
__device__ __forceinline__ float silu_f(float x){
  return x / (1.0f + __expf(-x));
}
__device__ __forceinline__ float softplus_f(float x){
  return fmaxf(x,0.0f) + log1pf(__expf(-fabsf(x)));
}

// ---- input projection + LN + gelu: u = gelu(LN(x@Win + bin)) ----
__global__ void k_input(const float* __restrict__ x, const float* __restrict__ Win,
                        const float* __restrict__ bin, const float* __restrict__ g,
                        const float* __restrict__ b, float* __restrict__ u){
  int r = blockIdx.x, t = threadIdx.x;
  __shared__ float xr[32];
  __shared__ float sA[4], sB[4];
  if(t<32) xr[t] = x[r*32+t];
  __syncthreads();
  float v = bin[t];
#pragma unroll
  for(int k=0;k<32;k++) v = fmaf(xr[k], Win[k*DM+t], v);
  float s = warpSum(v), sq = warpSum(v*v);
  if((t&63)==0){ sA[t>>6]=s; sB[t>>6]=sq; }
  __syncthreads();
  float mean = (sA[0]+sA[1]+sA[2]+sA[3])*(1.0f/DM);
  float msq  = (sB[0]+sB[1]+sB[2]+sB[3])*(1.0f/DM);
  float var = msq - mean*mean;
  float nv = (v-mean)*rsqrtf(var+1e-5f)*g[t]+b[t];
  u[r*DM+t] = gelu_f(nv);
}

// ---- rmsnorm over 256 ----
__global__ void k_rms(const float* __restrict__ u, const float* __restrict__ w, float* __restrict__ o){
  int r=blockIdx.x, t=threadIdx.x;
  __shared__ float sA[4];
  float v = u[r*DM+t];
  float sq = warpSum(v*v);
  if((t&63)==0) sA[t>>6]=sq;
  __syncthreads();
  float ms = (sA[0]+sA[1]+sA[2]+sA[3])*(1.0f/DM);
  o[r*DM+t] = v*rsqrtf(ms+1e-5f)*w[t];
}

// ---- layernorm over 256 ----
__global__ void k_ln(const float* __restrict__ u, const float* __restrict__ g,
                     const float* __restrict__ b, float* __restrict__ o){
  int r=blockIdx.x, t=threadIdx.x;
  __shared__ float sA[4], sB[4];
  float v = u[r*DM+t];
  float s = warpSum(v), sq = warpSum(v*v);
  if((t&63)==0){ sA[t>>6]=s; sB[t>>6]=sq; }
  __syncthreads();
  float mean = (sA[0]+sA[1]+sA[2]+sA[3])*(1.0f/DM);
  float msq  = (sB[0]+sB[1]+sB[2]+sB[3])*(1.0f/DM);
  float var = msq - mean*mean;
  o[r*DM+t] = (v-mean)*rsqrtf(var+1e-5f)*g[t]+b[t];
}

// ---- tiled fp32 GEMM: C[M,N] = A[M,K] @ W[K,N], EPI: 0=store,1=+R,2=gelu(+bias) ----
template<int EPI>
__global__ __launch_bounds__(256) void k_gemm(const float* __restrict__ A, const float* __restrict__ W,
                       const float* __restrict__ bias, const float* __restrict__ R,
                       float* __restrict__ C, int M, int K, int N){
  const int BM=128, BN=64, BK=16;
  __shared__ float As[BK][BM+4];
  __shared__ float Bs[BK][BN+4];
  int t = threadIdx.x;
  int tx = t&15, ty = t>>4;
  int m0 = blockIdx.y*BM, n0 = blockIdx.x*BN;
  float acc[8][4] = {};
  int arow = t>>1, ak = (t&1)*8;
  int brow = t>>4, bcol = (t&15)*4;
  for(int kt=0; kt<K; kt+=BK){
    float4 a0 = *(const float4*)&A[(m0+arow)*K + kt + ak];
    float4 a1 = *(const float4*)&A[(m0+arow)*K + kt + ak + 4];
    float4 bv = *(const float4*)&W[(kt+brow)*N + n0 + bcol];
    __syncthreads();
    As[ak+0][arow]=a0.x; As[ak+1][arow]=a0.y; As[ak+2][arow]=a0.z; As[ak+3][arow]=a0.w;
    As[ak+4][arow]=a1.x; As[ak+5][arow]=a1.y; As[ak+6][arow]=a1.z; As[ak+7][arow]=a1.w;
    *(float4*)&Bs[brow][bcol] = bv;
    __syncthreads();
#pragma unroll
    for(int k=0;k<BK;k++){
      float4 va0 = *(const float4*)&As[k][ty*8];
      float4 va1 = *(const float4*)&As[k][ty*8+4];
      float4 vb  = *(const float4*)&Bs[k][tx*4];
      float av[8] = {va0.x,va0.y,va0.z,va0.w,va1.x,va1.y,va1.z,va1.w};
      float bw[4] = {vb.x,vb.y,vb.z,vb.w};
#pragma unroll
      for(int i=0;i<8;i++)
#pragma unroll
        for(int j=0;j<4;j++)
          acc[i][j] = fmaf(av[i], bw[j], acc[i][j]);
    }
  }
#pragma unroll
  for(int i=0;i<8;i++){
    int row = m0 + ty*8 + i;
    int col = n0 + tx*4;
    float4 o;
    if(EPI==2){
      o.x = gelu_f(acc[i][0]+bias[col+0]);
      o.y = gelu_f(acc[i][1]+bias[col+1]);
      o.z = gelu_f(acc[i][2]+bias[col+2]);
      o.w = gelu_f(acc[i][3]+bias[col+3]);
    } else if(EPI==1){
      float4 rv = *(const float4*)&R[row*N+col];
      o.x = acc[i][0]+rv.x; o.y = acc[i][1]+rv.y;
      o.z = acc[i][2]+rv.z; o.w = acc[i][3]+rv.w;
    } else {
      o.x = acc[i][0]; o.y = acc[i][1]; o.z = acc[i][2]; o.w = acc[i][3];
    }
    *(float4*)&C[row*N+col] = o;
  }
}

// ---- causal depthwise conv (k=4) + bias + silu; xin = xz[:, :512] ----
__global__ void k_conv(const float* __restrict__ xz, const float* __restrict__ cw,
                       const float* __restrict__ cb, float* __restrict__ xs){
  int idx = blockIdx.x*blockDim.x + threadIdx.x; // L_SEQ*128 threads
  int l = idx>>7, c4 = (idx&127)*4;
  float acc[4];
#pragma unroll
  for(int j=0;j<4;j++) acc[j] = cb[c4+j];
#pragma unroll
  for(int k=0;k<4;k++){
    int ls = l-3+k;
    if(ls>=0){
      float4 xv = *(const float4*)&xz[ls*1024 + c4];
      acc[0] = fmaf(xv.x, cw[(c4+0)*4+k], acc[0]);
      acc[1] = fmaf(xv.y, cw[(c4+1)*4+k], acc[1]);
      acc[2] = fmaf(xv.z, cw[(c4+2)*4+k], acc[2]);
      acc[3] = fmaf(xv.w, cw[(c4+3)*4+k], acc[3]);
    }
  }
  float4 o = {silu_f(acc[0]),silu_f(acc[1]),silu_f(acc[2]),silu_f(acc[3])};
  *(float4*)&xs[l*DI + c4] = o;
}

// ---- dbc = xs @ xpW  (K=512, N=48), 16 rows per block ----
__global__ __launch_bounds__(256) void k_xproj(const float* __restrict__ xs,
                        const float* __restrict__ xpW, float* __restrict__ dbc){
  __shared__ float xsl[16][514];
  int t = threadIdx.x;
  int r0 = blockIdx.x*16;
#pragma unroll
  for(int i=0;i<32;i++){
    int idx = t + i*256;
    xsl[idx>>9][idx&511] = xs[(r0 + (idx>>9))*DI + (idx&511)];
  }
  __syncthreads();
  int row = t&15, cg = t>>4;
  float w0=0,w1=0,w2=0;
  for(int k=0;k<DI;k++){
    float xv = xsl[row][k];
    const float* wp = &xpW[k*48 + cg*3];
    w0 = fmaf(xv, wp[0], w0);
    w1 = fmaf(xv, wp[1], w1);
    w2 = fmaf(xv, wp[2], w2);
  }
  float* o = &dbc[(r0+row)*48 + cg*3];
  o[0]=w0; o[1]=w1; o[2]=w2;
}

// ---- delta = softplus(dbc[:, :16] @ dtW + dtB) ----
__global__ void k_delta(const float* __restrict__ dbc, const float* __restrict__ dtW,
                        const float* __restrict__ dtB, float* __restrict__ delta){
  int l = blockIdx.x>>1;
  int e = threadIdx.x + (blockIdx.x&1)*256;
  float s = dtB[e];
#pragma unroll
  for(int k=0;k<16;k++) s = fmaf(dbc[l*48+k], dtW[k*DI+e], s);
  delta[l*DI+e] = softplus_f(s);
}

// ---- scan phase 1 (thread-per-channel): per-chunk (prod dA, local carry) per state ----
__global__ __launch_bounds__(256) void k_scan1(const float* __restrict__ delta, const float* __restrict__ xs,
                        const float* __restrict__ dbc, const float* __restrict__ A_log,
                        float* __restrict__ Atot, float* __restrict__ Btot){
  int t = threadIdx.x;
  int chunk = blockIdx.x >> 1;
  int e = ((blockIdx.x & 1) << 8) + t;
  float A[16];
  {
    const float4* al = (const float4*)&A_log[e*DS];
#pragma unroll
    for(int q=0;q<4;q++){
      float4 a = al[q];
      A[q*4+0] = -__expf(a.x); A[q*4+1] = -__expf(a.y);
      A[q*4+2] = -__expf(a.z); A[q*4+3] = -__expf(a.w);
    }
  }
  float carry[16], aprod[16];
#pragma unroll
  for(int n=0;n<16;n++){ carry[n]=0.f; aprod[n]=1.f; }
  int l0 = chunk*CHL;
#pragma unroll 2
  for(int l=l0; l<l0+CHL; l++){
    float d  = delta[l*DI+e];
    float xv = xs[l*DI+e];
    float dxv = d*xv;
    const float4* bp = (const float4*)&dbc[l*48+16];
    float4 b0=bp[0], b1=bp[1], b2=bp[2], b3=bp[3];
    float B[16] = {b0.x,b0.y,b0.z,b0.w, b1.x,b1.y,b1.z,b1.w,
                   b2.x,b2.y,b2.z,b2.w, b3.x,b3.y,b3.z,b3.w};
#pragma unroll
    for(int n=0;n<16;n++){
      float dA = __expf(d*A[n]);
      carry[n] = fmaf(carry[n], dA, dxv*B[n]);
      aprod[n] *= dA;
    }
  }
  float4* ap = (float4*)&Atot[chunk*8192 + e*DS];
  float4* bp = (float4*)&Btot[chunk*8192 + e*DS];
#pragma unroll
  for(int q=0;q<4;q++){
    ap[q] = make_float4(aprod[q*4],aprod[q*4+1],aprod[q*4+2],aprod[q*4+3]);
    bp[q] = make_float4(carry[q*4],carry[q*4+1],carry[q*4+2],carry[q*4+3]);
  }
}

// ---- scan phase 2: carry-in per chunk (h0 may alias Btot: load-before-store) ----
__global__ void k_scan2(const float* __restrict__ Atot, const float* __restrict__ Btot,
                        float* __restrict__ h0){
  int tg = blockIdx.x*256 + threadIdx.x;
  float carry = 0.f;
  for(int c=0;c<NCH;c++){
    float a = Atot[c*8192+tg];
    float b = Btot[c*8192+tg];
    h0[c*8192+tg] = carry;
    carry = fmaf(carry, a, b);
  }
}

// ---- scan phase 3 (thread-per-channel): replay with carry-in,
//      fuse y = (sum_n h*C + xs*D) * silu(z) ----
__global__ __launch_bounds__(256) void k_scan3(const float* __restrict__ delta, const float* __restrict__ xs,
                        const float* __restrict__ dbc, const float* __restrict__ A_log,
                        const float* __restrict__ Dp, const float* __restrict__ h0,
                        const float* __restrict__ xz, float* __restrict__ y){
  int t = threadIdx.x;
  int chunk = blockIdx.x >> 1;
  int e = ((blockIdx.x & 1) << 8) + t;
  float A[16];
  {
    const float4* al = (const float4*)&A_log[e*DS];
#pragma unroll
    for(int q=0;q<4;q++){
      float4 a = al[q];
      A[q*4+0] = -__expf(a.x); A[q*4+1] = -__expf(a.y);
      A[q*4+2] = -__expf(a.z); A[q*4+3] = -__expf(a.w);
    }
  }
  float carry[16];
  {
    const float4* hp = (const float4*)&h0[chunk*8192 + e*DS];
#pragma unroll
    for(int q=0;q<4;q++){
      float4 h = hp[q];
      carry[q*4+0]=h.x; carry[q*4+1]=h.y; carry[q*4+2]=h.z; carry[q*4+3]=h.w;
    }
  }
  float Dv = Dp[e];
  int l0 = chunk*CHL;
#pragma unroll 2
  for(int l=l0; l<l0+CHL; l++){
    float d  = delta[l*DI+e];
    float xv = xs[l*DI+e];
    float dxv = d*xv;
    const float4* bp = (const float4*)&dbc[l*48+16];
    float4 b0=bp[0], b1=bp[1], b2=bp[2], b3=bp[3];
    float4 c0=bp[4], c1=bp[5], c2=bp[6], c3=bp[7];
    float B[16] = {b0.x,b0.y,b0.z,b0.w, b1.x,b1.y,b1.z,b1.w,
                   b2.x,b2.y,b2.z,b2.w, b3.x,b3.y,b3.z,b3.w};
    float Cv[16] = {c0.x,c0.y,c0.z,c0.w, c1.x,c1.y,c1.z,c1.w,
                    c2.x,c2.y,c2.z,c2.w, c3.x,c3.y,c3.z,c3.w};
    float p[4] = {0.f,0.f,0.f,0.f};
#pragma unroll
    for(int n=0;n<16;n++){
      float dA = __expf(d*A[n]);
      carry[n] = fmaf(carry[n], dA, dxv*B[n]);
      p[n&3] = fmaf(carry[n], Cv[n], p[n&3]);
    }
    float ps = (p[0]+p[1]) + (p[2]+p[3]);
    float z = xz[l*1024 + 512 + e];
    y[l*DI+e] = fmaf(xv, Dv, ps) * silu_f(z);
  }
}

// ---- final: LN(128) -> @W2(128,1)+b2 -> tanh, one wave per row ----
__global__ void k_final(const float* __restrict__ h2, const float* __restrict__ g,
                        const float* __restrict__ b, const float* __restrict__ W2,
                        const float* __restrict__ b2, float* __restrict__ out){
  int lane = threadIdx.x&63;
  int wv = threadIdx.x>>6;
  int r = blockIdx.x*4 + wv;
  float v0 = h2[r*128+lane], v1 = h2[r*128+64+lane];
  float s = v0+v1, sq = v0*v0+v1*v1;
#pragma unroll
  for(int o=32;o;o>>=1){ s += __shfl_xor(s,o); sq += __shfl_xor(sq,o); }
  float mean = s*(1.0f/128), var = sq*(1.0f/128) - mean*mean;
  float rs = rsqrtf(var+1e-5f);
  float n0 = (v0-mean)*rs*g[lane]+b[lane];
  float n1 = (v1-mean)*rs*g[lane+64]+b[lane+64];
  float d = n0*W2[lane] + n1*W2[lane+64];
#pragma unroll
  for(int o=32;o;o>>=1) d += __shfl_xor(d,o);
  if(lane==0) out[r] = tanhf(d + b2[0]);
}

extern "C" void kernel_launch(void* const* d_in, const int* in_sizes, int n_in,
                              void* d_out, int out_size, void* d_ws, size_t ws_size,
                              hipStream_t stream){
  const float* x    = (const float*)d_in[0];
  const float* Win  = (const float*)d_in[1];
  const float* bin  = (const float*)d_in[2];
  const float* ln1g = (const float*)d_in[3];
  const float* ln1b = (const float*)d_in[4];
  const float* rmsw = (const float*)d_in[5];
  const float* inW  = (const float*)d_in[6];
  const float* convW= (const float*)d_in[7];
  const float* convB= (const float*)d_in[8];
  const float* xpW  = (const float*)d_in[9];
  const float* dtW  = (const float*)d_in[10];
  const float* dtB  = (const float*)d_in[11];
  const float* A_log= (const float*)d_in[12];
  const float* Dp   = (const float*)d_in[13];
  const float* outW = (const float*)d_in[14];
  const float* ln2g = (const float*)d_in[15];
  const float* ln2b = (const float*)d_in[16];
  const float* W1   = (const float*)d_in[17];
  const float* b1   = (const float*)d_in[18];
  const float* ln3g = (const float*)d_in[19];
  const float* ln3b = (const float*)d_in[20];
  const float* W2   = (const float*)d_in[21];
  const float* b2   = (const float*)d_in[22];
  float* out = (float*)d_out;
  float* ws = (float*)d_ws;
  float* u    = ws;                    // 16384*256
  float* hn   = ws + 4194304;          // 16384*256
  float* xz   = ws + 8388608;          // 16384*1024
  float* xs   = ws + 25165824;         // 16384*512
  float* dbc  = ws + 33554432;         // 16384*48
  float* delta= ws + 34340864;         // 16384*512
  float* y    = ws + 42729472;         // 16384*512
  float* Atot = ws + 51118080;         // NCH*8192 = 2097152
  float* Btot = ws + 53215232;         // NCH*8192 = 2097152
  float* h0   = Btot;                  // aliased (scan2 loads before store)
  float* h2   = u;                     // aliased (u dead after k_ln)

  k_input<<<L_SEQ,256,0,stream>>>(x,Win,bin,ln1g,ln1b,u);
  for(int i=0;i<2;i++){
    k_rms<<<L_SEQ,256,0,stream>>>(u, rmsw+i*DM, hn);
    k_gemm<0><<<dim3(1024/64, L_SEQ/128),256,0,stream>>>(hn, inW+i*DM*1024, nullptr, nullptr, xz, L_SEQ, DM, 1024);
    k_conv<<<L_SEQ*128/256,256,0,stream>>>(xz, convW+i*DI*4, convB+i*DI, xs);
    k_xproj<<<L_SEQ/16,256,0,stream>>>(xs, xpW+i*DI*48, dbc);
    k_delta<<<L_SEQ*2,256,0,stream>>>(dbc, dtW+i*16*DI, dtB+i*DI, delta);
    k_scan1<<<NCH*2,256,0,stream>>>(delta, xs, dbc, A_log+i*DI*DS, Atot, Btot);
    k_scan2<<<32,256,0,stream>>>(Atot, Btot, h0);
    k_scan3<<<NCH*2,256,0,stream>>>(delta, xs, dbc, A_log+i*DI*DS, Dp+i*DI, h0, xz, y);
    k_gemm<1><<<dim3(DM/64, L_SEQ/128),256,0,stream>>>(y, outW+i*DI*DM, nullptr, u, u, L_SEQ, DI, DM);
  }
  k_ln<<<L_SEQ,256,0,stream>>>(u, ln2g, ln2b, hn);
  k_gemm<2><<<dim3(128/64, L_SEQ/128),256,0,stream>>>(hn, W1, b1, nullptr, h2, L_SEQ, DM, 128);
  k_final<<<L_SEQ/4,256,0,stream>>>(h2, ln3g, ln3b, W2, b2, out);
}

// Round 3
// 692.956 us; speedup vs baseline: 1.7694x; 1.4492x over previous
//
#include <hip/hip_runtime.h>
#include <hip/hip_bf16.h>
#include <math.h>

#define L_SEQ 16384
#define DM 256
#define DI 512
#define DS 16
#define NCH 256   // number of scan chunks
#define CHL 64    // chunk length (NCH*CHL == L_SEQ)

typedef __attribute__((ext_vector_type(8))) short short8v;
typedef __attribute__((ext_vector_type(4))) float f32x4;

__device__ __forceinline__ float warpSum(float v){
#pragma unroll
  for(int o=32;o;o>>=1) v += __shfl_xor(v,o);
  return v;
}
__device__ __forceinline__ float gelu_f(float x){
  float x3 = x*x*x;
  return 0.5f*x*(1.0f + tanhf(0.7978845608028654f*(x + 0.044715f*x3)));
}
__device__ __forceinline__ float silu_f(float x){
  return x / (1.0f + __expf(-x));
}
__device__ __forceinline__ float softplus_f(float x){
  return fmaxf(x,0.0f) + log1pf(__expf(-fabsf(x)));
}
__device__ __forceinline__ void gload16(const void* g, void* l){
  __builtin_amdgcn_global_load_lds((const __attribute__((address_space(1))) void*)g,
                                   (__attribute__((address_space(3))) void*)l, 16, 0, 0);
}

// ---- weight convert + transpose to bf16: Wt[n][k] = bf16(W[k][n]) ----
__global__ void k_cvtw(const float* __restrict__ inW, const float* __restrict__ outW,
                       const float* __restrict__ W1, __hip_bfloat16* __restrict__ inWt,
                       __hip_bfloat16* __restrict__ outWt, __hip_bfloat16* __restrict__ W1t){
  int idx = blockIdx.x*256 + threadIdx.x;
  if(idx < 524288){                      // inW: 2 layers of [256][1024] -> [1024][256]
    int layer = idx >> 18;
    int r = idx & 262143;
    int n = r >> 8, k = r & 255;
    inWt[idx] = __float2bfloat16(inW[layer*262144 + k*1024 + n]);
  } else if(idx < 786432){               // outW: 2 layers of [512][256] -> [256][512]
    int j = idx - 524288;
    int layer = j >> 17;
    int r = j & 131071;
    int n = r >> 9, k = r & 511;
    outWt[j] = __float2bfloat16(outW[layer*131072 + k*256 + n]);
  } else if(idx < 819200){               // W1: [256][128] -> [128][256]
    int j = idx - 786432;
    int n = j >> 8, k = j & 255;
    W1t[j] = __float2bfloat16(W1[k*128 + n]);
  }
}

// ---- input projection + LN + gelu: u = gelu(LN(x@Win + bin)) ----
__global__ void k_input(const float* __restrict__ x, const float* __restrict__ Win,
                        const float* __restrict__ bin, const float* __restrict__ g,
                        const float* __restrict__ b, float* __restrict__ u){
  int r = blockIdx.x, t = threadIdx.x;
  __shared__ float xr[32];
  __shared__ float sA[4], sB[4];
  if(t<32) xr[t] = x[r*32+t];
  __syncthreads();
  float v = bin[t];
#pragma unroll
  for(int k=0;k<32;k++) v = fmaf(xr[k], Win[k*DM+t], v);
  float s = warpSum(v), sq = warpSum(v*v);
  if((t&63)==0){ sA[t>>6]=s; sB[t>>6]=sq; }
  __syncthreads();
  float mean = (sA[0]+sA[1]+sA[2]+sA[3])*(1.0f/DM);
  float msq  = (sB[0]+sB[1]+sB[2]+sB[3])*(1.0f/DM);
  float var = msq - mean*mean;
  float nv = (v-mean)*rsqrtf(var+1e-5f)*g[t]+b[t];
  u[r*DM+t] = gelu_f(nv);
}

// ---- rmsnorm over 256 -> bf16 ----
__global__ void k_rms(const float* __restrict__ u, const float* __restrict__ w,
                      __hip_bfloat16* __restrict__ o){
  int r=blockIdx.x, t=threadIdx.x;
  __shared__ float sA[4];
  float v = u[r*DM+t];
  float sq = warpSum(v*v);
  if((t&63)==0) sA[t>>6]=sq;
  __syncthreads();
  float ms = (sA[0]+sA[1]+sA[2]+sA[3])*(1.0f/DM);
  o[r*DM+t] = __float2bfloat16(v*rsqrtf(ms+1e-5f)*w[t]);
}

// ---- layernorm over 256 -> bf16 ----
__global__ void k_ln(const float* __restrict__ u, const float* __restrict__ g,
                     const float* __restrict__ b, __hip_bfloat16* __restrict__ o){
  int r=blockIdx.x, t=threadIdx.x;
  __shared__ float sA[4], sB[4];
  float v = u[r*DM+t];
  float s = warpSum(v), sq = warpSum(v*v);
  if((t&63)==0){ sA[t>>6]=s; sB[t>>6]=sq; }
  __syncthreads();
  float mean = (sA[0]+sA[1]+sA[2]+sA[3])*(1.0f/DM);
  float msq  = (sB[0]+sB[1]+sB[2]+sB[3])*(1.0f/DM);
  float var = msq - mean*mean;
  o[r*DM+t] = __float2bfloat16((v-mean)*rsqrtf(var+1e-5f)*g[t]+b[t]);
}

// ---- bf16 MFMA GEMM: C[M,N](f32) = A[M,K](bf16) @ Wt[N,K](bf16)^T
//      EPI: 0=store, 1=+R, 2=gelu(+bias). BM=BN=128, BK=64, 4 waves. ----
template<int EPI>
__global__ __launch_bounds__(256) void k_mgemm(const __hip_bfloat16* __restrict__ A,
    const __hip_bfloat16* __restrict__ Wt, const float* __restrict__ bias,
    const float* __restrict__ R, float* __restrict__ C, int M, int K, int N){
  __shared__ short As[8192];   // [128 rows][64 k] bf16, slot-swizzled
  __shared__ short Bs[8192];
  int t = threadIdx.x, lane = t&63, wave = t>>6;
  int m0 = blockIdx.y*128, n0 = blockIdx.x*128;
  int wm = (wave>>1)*64, wn = (wave&1)*64;
  f32x4 acc[4][4] = {};
  // staging descriptors: LDS linear dest (base+lane*16), pre-swizzled global src
  int soff[4], srow[4], scol[4];
#pragma unroll
  for(int c=0;c<4;c++){
    int off = (wave*4+c)*1024 + lane*16;   // byte offset in 16KB tile
    int row = off>>7;                       // 128B per row
    int sl  = ((off>>4)&7) ^ (row&7);       // logical 16B slot for this phys slot
    soff[c]=off; srow[c]=row; scol[c]=sl*8;
  }
  for(int kt=0; kt<K; kt+=64){
#pragma unroll
    for(int c=0;c<4;c++){
      gload16(&A [(m0+srow[c])*K + kt + scol[c]], (char*)As + soff[c]);
      gload16(&Wt[(n0+srow[c])*K + kt + scol[c]], (char*)Bs + soff[c]);
    }
    asm volatile("s_waitcnt vmcnt(0)" ::: "memory");
    __syncthreads();
#pragma unroll
    for(int ks=0; ks<2; ks++){
      short8v a[4], b[4];
      int k8 = ks*4 + (lane>>4);
#pragma unroll
      for(int i=0;i<4;i++){
        int lr = wm + i*16 + (lane&15);
        a[i] = *(const short8v*)&As[lr*64 + (k8 ^ (lr&7))*8];
      }
#pragma unroll
      for(int j=0;j<4;j++){
        int lr = wn + j*16 + (lane&15);
        b[j] = *(const short8v*)&Bs[lr*64 + (k8 ^ (lr&7))*8];
      }
#pragma unroll
      for(int i=0;i<4;i++)
#pragma unroll
        for(int j=0;j<4;j++)
          acc[i][j] = __builtin_amdgcn_mfma_f32_16x16x32_bf16(a[i], b[j], acc[i][j], 0,0,0);
    }
    __syncthreads();
  }
#pragma unroll
  for(int i=0;i<4;i++){
    int grow0 = m0 + wm + i*16 + (lane>>4)*4;
#pragma unroll
    for(int j=0;j<4;j++){
      int gcol = n0 + wn + j*16 + (lane&15);
#pragma unroll
      for(int r=0;r<4;r++){
        float v = acc[i][j][r];
        int grow = grow0 + r;
        if(EPI==1) v += R[grow*N+gcol];
        if(EPI==2) v = gelu_f(v + bias[gcol]);
        C[grow*N+gcol] = v;
      }
    }
  }
}

// ---- causal depthwise conv (k=4) + bias + silu; xin = xz[:, :512] ----
__global__ void k_conv(const float* __restrict__ xz, const float* __restrict__ cw,
                       const float* __restrict__ cb, float* __restrict__ xs){
  int idx = blockIdx.x*blockDim.x + threadIdx.x; // L_SEQ*128 threads
  int l = idx>>7, c4 = (idx&127)*4;
  float acc[4];
#pragma unroll
  for(int j=0;j<4;j++) acc[j] = cb[c4+j];
#pragma unroll
  for(int k=0;k<4;k++){
    int ls = l-3+k;
    if(ls>=0){
      float4 xv = *(const float4*)&xz[ls*1024 + c4];
      acc[0] = fmaf(xv.x, cw[(c4+0)*4+k], acc[0]);
      acc[1] = fmaf(xv.y, cw[(c4+1)*4+k], acc[1]);
      acc[2] = fmaf(xv.z, cw[(c4+2)*4+k], acc[2]);
      acc[3] = fmaf(xv.w, cw[(c4+3)*4+k], acc[3]);
    }
  }
  float4 o = {silu_f(acc[0]),silu_f(acc[1]),silu_f(acc[2]),silu_f(acc[3])};
  *(float4*)&xs[l*DI + c4] = o;
}

// ---- dbc = xs @ xpW  (K=512, N=48), 16 rows per block ----
__global__ __launch_bounds__(256) void k_xproj(const float* __restrict__ xs,
                        const float* __restrict__ xpW, float* __restrict__ dbc){
  __shared__ float xsl[16][514];
  int t = threadIdx.x;
  int r0 = blockIdx.x*16;
#pragma unroll
  for(int i=0;i<32;i++){
    int idx = t + i*256;
    xsl[idx>>9][idx&511] = xs[(r0 + (idx>>9))*DI + (idx&511)];
  }
  __syncthreads();
  int row = t&15, cg = t>>4;
  float w0=0,w1=0,w2=0;
  for(int k=0;k<DI;k++){
    float xv = xsl[row][k];
    const float* wp = &xpW[k*48 + cg*3];
    w0 = fmaf(xv, wp[0], w0);
    w1 = fmaf(xv, wp[1], w1);
    w2 = fmaf(xv, wp[2], w2);
  }
  float* o = &dbc[(r0+row)*48 + cg*3];
  o[0]=w0; o[1]=w1; o[2]=w2;
}

// ---- delta = softplus(dbc[:, :16] @ dtW + dtB) ----
__global__ void k_delta(const float* __restrict__ dbc, const float* __restrict__ dtW,
                        const float* __restrict__ dtB, float* __restrict__ delta){
  int l = blockIdx.x>>1;
  int e = threadIdx.x + (blockIdx.x&1)*256;
  float s = dtB[e];
#pragma unroll
  for(int k=0;k<16;k++) s = fmaf(dbc[l*48+k], dtW[k*DI+e], s);
  delta[l*DI+e] = softplus_f(s);
}

// ---- scan phase 1 (thread-per-channel): per-chunk (prod dA, local carry) per state ----
__global__ __launch_bounds__(256) void k_scan1(const float* __restrict__ delta, const float* __restrict__ xs,
                        const float* __restrict__ dbc, const float* __restrict__ A_log,
                        float* __restrict__ Atot, float* __restrict__ Btot){
  int t = threadIdx.x;
  int chunk = blockIdx.x >> 1;
  int e = ((blockIdx.x & 1) << 8) + t;
  float A[16];
  {
    const float4* al = (const float4*)&A_log[e*DS];
#pragma unroll
    for(int q=0;q<4;q++){
      float4 a = al[q];
      A[q*4+0] = -__expf(a.x); A[q*4+1] = -__expf(a.y);
      A[q*4+2] = -__expf(a.z); A[q*4+3] = -__expf(a.w);
    }
  }
  float carry[16], aprod[16];
#pragma unroll
  for(int n=0;n<16;n++){ carry[n]=0.f; aprod[n]=1.f; }
  int l0 = chunk*CHL;
#pragma unroll 2
  for(int l=l0; l<l0+CHL; l++){
    float d  = delta[l*DI+e];
    float xv = xs[l*DI+e];
    float dxv = d*xv;
    const float4* bp = (const float4*)&dbc[l*48+16];
    float4 b0=bp[0], b1=bp[1], b2=bp[2], b3=bp[3];
    float B[16] = {b0.x,b0.y,b0.z,b0.w, b1.x,b1.y,b1.z,b1.w,
                   b2.x,b2.y,b2.z,b2.w, b3.x,b3.y,b3.z,b3.w};
#pragma unroll
    for(int n=0;n<16;n++){
      float dA = __expf(d*A[n]);
      carry[n] = fmaf(carry[n], dA, dxv*B[n]);
      aprod[n] *= dA;
    }
  }
  float4* ap = (float4*)&Atot[chunk*8192 + e*DS];
  float4* bp = (float4*)&Btot[chunk*8192 + e*DS];
#pragma unroll
  for(int q=0;q<4;q++){
    ap[q] = make_float4(aprod[q*4],aprod[q*4+1],aprod[q*4+2],aprod[q*4+3]);
    bp[q] = make_float4(carry[q*4],carry[q*4+1],carry[q*4+2],carry[q*4+3]);
  }
}

// ---- scan phase 2: carry-in per chunk (h0 may alias Btot: load-before-store) ----
__global__ void k_scan2(const float* __restrict__ Atot, const float* __restrict__ Btot,
                        float* __restrict__ h0){
  int tg = blockIdx.x*256 + threadIdx.x;
  float carry = 0.f;
  for(int c=0;c<NCH;c++){
    float a = Atot[c*8192+tg];
    float b = Btot[c*8192+tg];
    h0[c*8192+tg] = carry;
    carry = fmaf(carry, a, b);
  }
}

// ---- scan phase 3 (thread-per-channel): replay with carry-in,
//      fuse y = (sum_n h*C + xs*D) * silu(z), output bf16 ----
__global__ __launch_bounds__(256) void k_scan3(const float* __restrict__ delta, const float* __restrict__ xs,
                        const float* __restrict__ dbc, const float* __restrict__ A_log,
                        const float* __restrict__ Dp, const float* __restrict__ h0,
                        const float* __restrict__ xz, __hip_bfloat16* __restrict__ y){
  int t = threadIdx.x;
  int chunk = blockIdx.x >> 1;
  int e = ((blockIdx.x & 1) << 8) + t;
  float A[16];
  {
    const float4* al = (const float4*)&A_log[e*DS];
#pragma unroll
    for(int q=0;q<4;q++){
      float4 a = al[q];
      A[q*4+0] = -__expf(a.x); A[q*4+1] = -__expf(a.y);
      A[q*4+2] = -__expf(a.z); A[q*4+3] = -__expf(a.w);
    }
  }
  float carry[16];
  {
    const float4* hp = (const float4*)&h0[chunk*8192 + e*DS];
#pragma unroll
    for(int q=0;q<4;q++){
      float4 h = hp[q];
      carry[q*4+0]=h.x; carry[q*4+1]=h.y; carry[q*4+2]=h.z; carry[q*4+3]=h.w;
    }
  }
  float Dv = Dp[e];
  int l0 = chunk*CHL;
#pragma unroll 2
  for(int l=l0; l<l0+CHL; l++){
    float d  = delta[l*DI+e];
    float xv = xs[l*DI+e];
    float dxv = d*xv;
    const float4* bp = (const float4*)&dbc[l*48+16];
    float4 b0=bp[0], b1=bp[1], b2=bp[2], b3=bp[3];
    float4 c0=bp[4], c1=bp[5], c2=bp[6], c3=bp[7];
    float B[16] = {b0.x,b0.y,b0.z,b0.w, b1.x,b1.y,b1.z,b1.w,
                   b2.x,b2.y,b2.z,b2.w, b3.x,b3.y,b3.z,b3.w};
    float Cv[16] = {c0.x,c0.y,c0.z,c0.w, c1.x,c1.y,c1.z,c1.w,
                    c2.x,c2.y,c2.z,c2.w, c3.x,c3.y,c3.z,c3.w};
    float p[4] = {0.f,0.f,0.f,0.f};
#pragma unroll
    for(int n=0;n<16;n++){
      float dA = __expf(d*A[n]);
      carry[n] = fmaf(carry[n], dA, dxv*B[n]);
      p[n&3] = fmaf(carry[n], Cv[n], p[n&3]);
    }
    float ps = (p[0]+p[1]) + (p[2]+p[3]);
    float z = xz[l*1024 + 512 + e];
    y[l*DI+e] = __float2bfloat16(fmaf(xv, Dv, ps) * silu_f(z));
  }
}

// ---- final: LN(128) -> @W2(128,1)+b2 -> tanh, one wave per row ----
__global__ void k_final(const float* __restrict__ h2, const float* __restrict__ g,
                        const float* __restrict__ b, const float* __restrict__ W2,
                        const float* __restrict__ b2, float* __restrict__ out){
  int lane = threadIdx.x&63;
  int wv = threadIdx.x>>6;
  int r = blockIdx.x*4 + wv;
  float v0 = h2[r*128+lane], v1 = h2[r*128+64+lane];
  float s = v0+v1, sq = v0*v0+v1*v1;
#pragma unroll
  for(int o=32;o;o>>=1){ s += __shfl_xor(s,o); sq += __shfl_xor(sq,o); }
  float mean = s*(1.0f/128), var = sq*(1.0f/128) - mean*mean;
  float rs = rsqrtf(var+1e-5f);
  float n0 = (v0-mean)*rs*g[lane]+b[lane];
  float n1 = (v1-mean)*rs*g[lane+64]+b[lane+64];
  float d = n0*W2[lane] + n1*W2[lane+64];
#pragma unroll
  for(int o=32;o;o>>=1) d += __shfl_xor(d,o);
  if(lane==0) out[r] = tanhf(d + b2[0]);
}

extern "C" void kernel_launch(void* const* d_in, const int* in_sizes, int n_in,
                              void* d_out, int out_size, void* d_ws, size_t ws_size,
                              hipStream_t stream){
  const float* x    = (const float*)d_in[0];
  const float* Win  = (const float*)d_in[1];
  const float* bin  = (const float*)d_in[2];
  const float* ln1g = (const float*)d_in[3];
  const float* ln1b = (const float*)d_in[4];
  const float* rmsw = (const float*)d_in[5];
  const float* inW  = (const float*)d_in[6];
  const float* convW= (const float*)d_in[7];
  const float* convB= (const float*)d_in[8];
  const float* xpW  = (const float*)d_in[9];
  const float* dtW  = (const float*)d_in[10];
  const float* dtB  = (const float*)d_in[11];
  const float* A_log= (const float*)d_in[12];
  const float* Dp   = (const float*)d_in[13];
  const float* outW = (const float*)d_in[14];
  const float* ln2g = (const float*)d_in[15];
  const float* ln2b = (const float*)d_in[16];
  const float* W1   = (const float*)d_in[17];
  const float* b1   = (const float*)d_in[18];
  const float* ln3g = (const float*)d_in[19];
  const float* ln3b = (const float*)d_in[20];
  const float* W2   = (const float*)d_in[21];
  const float* b2   = (const float*)d_in[22];
  float* out = (float*)d_out;
  float* ws = (float*)d_ws;
  float* u    = ws;                    // 16384*256 f32
  __hip_bfloat16* hn_bf = (__hip_bfloat16*)(ws + 4194304);   // 16384*256 bf16
  float* xz   = ws + 8388608;          // 16384*1024 f32
  float* xs   = ws + 25165824;         // 16384*512 f32
  float* dbc  = ws + 33554432;         // 16384*48 f32
  float* delta= ws + 34340864;         // 16384*512 f32
  __hip_bfloat16* y_bf = (__hip_bfloat16*)(ws + 42729472);   // 16384*512 bf16
  float* Atot = ws + 51118080;         // NCH*8192
  float* Btot = ws + 53215232;         // NCH*8192
  float* h0   = Btot;                  // aliased (scan2 loads before store)
  float* h2   = u;                     // aliased (u dead after k_ln)
  __hip_bfloat16* inWt  = (__hip_bfloat16*)(ws + 55312384);  // 2*1024*256 bf16
  __hip_bfloat16* outWt = (__hip_bfloat16*)(ws + 55574528);  // 2*256*512 bf16
  __hip_bfloat16* W1t   = (__hip_bfloat16*)(ws + 55705600);  // 128*256 bf16

  k_cvtw<<<3200,256,0,stream>>>(inW, outW, W1, inWt, outWt, W1t);
  k_input<<<L_SEQ,256,0,stream>>>(x,Win,bin,ln1g,ln1b,u);
  for(int i=0;i<2;i++){
    k_rms<<<L_SEQ,256,0,stream>>>(u, rmsw+i*DM, hn_bf);
    k_mgemm<0><<<dim3(8, L_SEQ/128),256,0,stream>>>(hn_bf, inWt+i*262144, nullptr, nullptr, xz, L_SEQ, DM, 1024);
    k_conv<<<L_SEQ*128/256,256,0,stream>>>(xz, convW+i*DI*4, convB+i*DI, xs);
    k_xproj<<<L_SEQ/16,256,0,stream>>>(xs, xpW+i*DI*48, dbc);
    k_delta<<<L_SEQ*2,256,0,stream>>>(dbc, dtW+i*16*DI, dtB+i*DI, delta);
    k_scan1<<<NCH*2,256,0,stream>>>(delta, xs, dbc, A_log+i*DI*DS, Atot, Btot);
    k_scan2<<<32,256,0,stream>>>(Atot, Btot, h0);
    k_scan3<<<NCH*2,256,0,stream>>>(delta, xs, dbc, A_log+i*DI*DS, Dp+i*DI, h0, xz, y_bf);
    k_mgemm<1><<<dim3(2, L_SEQ/128),256,0,stream>>>(y_bf, outWt+i*131072, nullptr, u, u, L_SEQ, DI, DM);
  }
  k_ln<<<L_SEQ,256,0,stream>>>(u, ln2g, ln2b, hn_bf);
  k_mgemm<2><<<dim3(1, L_SEQ/128),256,0,stream>>>(hn_bf, W1t, b1, nullptr, h2, L_SEQ, DM, 128);
  k_final<<<L_SEQ/4,256,0,stream>>>(h2, ln3g, ln3b, W2, b2, out);
}

// Round 4
// 624.120 us; speedup vs baseline: 1.9645x; 1.1103x over previous
//
#include <hip/hip_runtime.h>
#include <hip/hip_bf16.h>
#include <math.h>

#define L_SEQ 16384
#define DM 256
#define DI 512
#define DS 16
#define NCH 256   // number of scan chunks
#define CHL 64    // chunk length (NCH*CHL == L_SEQ)

typedef __attribute__((ext_vector_type(8))) short short8v;
typedef __attribute__((ext_vector_type(4))) float f32x4;

__device__ __forceinline__ float warpSum(float v){
#pragma unroll
  for(int o=32;o;o>>=1) v += __shfl_xor(v,o);
  return v;
}
__device__ __forceinline__ float gelu_f(float x){
  float x3 = x*x*x;
  return 0.5f*x*(1.0f + tanhf(0.7978845608028654f*(x + 0.044715f*x3)));
}
__device__ __forceinline__ float silu_f(float x){
  return x / (1.0f + __expf(-x));
}
__device__ __forceinline__ float softplus_f(float x){
  return fmaxf(x,0.0f) + log1pf(__expf(-fabsf(x)));
}
__device__ __forceinline__ void gload16(const void* g, void* l){
  __builtin_amdgcn_global_load_lds((const __attribute__((address_space(1))) void*)g,
                                   (__attribute__((address_space(3))) void*)l, 16, 0, 0);
}

// ---- weight convert + transpose to bf16: Wt[n][k] = bf16(W[k][n]) ----
__global__ void k_cvtw(const float* __restrict__ inW, const float* __restrict__ outW,
                       const float* __restrict__ W1, __hip_bfloat16* __restrict__ inWt,
                       __hip_bfloat16* __restrict__ outWt, __hip_bfloat16* __restrict__ W1t){
  int idx = blockIdx.x*256 + threadIdx.x;
  if(idx < 524288){                      // inW: 2 layers of [256][1024] -> [1024][256]
    int layer = idx >> 18;
    int r = idx & 262143;
    int n = r >> 8, k = r & 255;
    inWt[idx] = __float2bfloat16(inW[layer*262144 + k*1024 + n]);
  } else if(idx < 786432){               // outW: 2 layers of [512][256] -> [256][512]
    int j = idx - 524288;
    int layer = j >> 17;
    int r = j & 131071;
    int n = r >> 9, k = r & 511;
    outWt[j] = __float2bfloat16(outW[layer*131072 + k*256 + n]);
  } else if(idx < 819200){               // W1: [256][128] -> [128][256]
    int j = idx - 786432;
    int n = j >> 8, k = j & 255;
    W1t[j] = __float2bfloat16(W1[k*128 + n]);
  }
}

// ---- fold xpW/dtW: Wd_t[layer][n][k] = sum_j xpW[k][j]*dtW[j][n] (delta pre-act),
//      Wbc_t[layer][n][k] = xpW[k][16+n] for n<32, 0 pad to 128 rows ----
__global__ void k_wd(const float* __restrict__ xpW, const float* __restrict__ dtW,
                     __hip_bfloat16* __restrict__ Wd_t, __hip_bfloat16* __restrict__ Wbc_t){
  int idx = blockIdx.x*256 + threadIdx.x;
  if(idx < 524288){                      // 2 layers x [512 n][512 k]
    int layer = idx >> 18;
    int r = idx & 262143;
    int n = r >> 9, k = r & 511;
    const float* xp = xpW + layer*512*48;
    const float* dt = dtW + layer*16*512;
    float s = 0.f;
#pragma unroll
    for(int j=0;j<16;j++) s = fmaf(xp[k*48+j], dt[j*512+n], s);
    Wd_t[idx] = __float2bfloat16(s);
  } else if(idx < 655360){               // 2 layers x [128 n][512 k]
    int j2 = idx - 524288;
    int layer = j2 >> 16;
    int r = j2 & 65535;
    int n = r >> 9, k = r & 511;
    float v = (n < 32) ? xpW[layer*512*48 + k*48 + 16 + n] : 0.f;
    Wbc_t[j2] = __float2bfloat16(v);
  }
}

// ---- input projection + LN + gelu: u = gelu(LN(x@Win + bin)) ----
__global__ void k_input(const float* __restrict__ x, const float* __restrict__ Win,
                        const float* __restrict__ bin, const float* __restrict__ g,
                        const float* __restrict__ b, float* __restrict__ u){
  int r = blockIdx.x, t = threadIdx.x;
  __shared__ float xr[32];
  __shared__ float sA[4], sB[4];
  if(t<32) xr[t] = x[r*32+t];
  __syncthreads();
  float v = bin[t];
#pragma unroll
  for(int k=0;k<32;k++) v = fmaf(xr[k], Win[k*DM+t], v);
  float s = warpSum(v), sq = warpSum(v*v);
  if((t&63)==0){ sA[t>>6]=s; sB[t>>6]=sq; }
  __syncthreads();
  float mean = (sA[0]+sA[1]+sA[2]+sA[3])*(1.0f/DM);
  float msq  = (sB[0]+sB[1]+sB[2]+sB[3])*(1.0f/DM);
  float var = msq - mean*mean;
  float nv = (v-mean)*rsqrtf(var+1e-5f)*g[t]+b[t];
  u[r*DM+t] = gelu_f(nv);
}

// ---- rmsnorm over 256 -> bf16 ----
__global__ void k_rms(const float* __restrict__ u, const float* __restrict__ w,
                      __hip_bfloat16* __restrict__ o){
  int r=blockIdx.x, t=threadIdx.x;
  __shared__ float sA[4];
  float v = u[r*DM+t];
  float sq = warpSum(v*v);
  if((t&63)==0) sA[t>>6]=sq;
  __syncthreads();
  float ms = (sA[0]+sA[1]+sA[2]+sA[3])*(1.0f/DM);
  o[r*DM+t] = __float2bfloat16(v*rsqrtf(ms+1e-5f)*w[t]);
}

// ---- layernorm over 256 -> bf16 ----
__global__ void k_ln(const float* __restrict__ u, const float* __restrict__ g,
                     const float* __restrict__ b, __hip_bfloat16* __restrict__ o){
  int r=blockIdx.x, t=threadIdx.x;
  __shared__ float sA[4], sB[4];
  float v = u[r*DM+t];
  float s = warpSum(v), sq = warpSum(v*v);
  if((t&63)==0){ sA[t>>6]=s; sB[t>>6]=sq; }
  __syncthreads();
  float mean = (sA[0]+sA[1]+sA[2]+sA[3])*(1.0f/DM);
  float msq  = (sB[0]+sB[1]+sB[2]+sB[3])*(1.0f/DM);
  float var = msq - mean*mean;
  o[r*DM+t] = __float2bfloat16((v-mean)*rsqrtf(var+1e-5f)*g[t]+b[t]);
}

// ---- bf16 MFMA GEMM: C[M,:](f32, stride ldc) = A[M,K](bf16) @ Wt[N,K](bf16)^T
//      EPI: 0=store, 1=+R, 2=gelu(+bias), 3=softplus(+bias). Stores cols < Nout. ----
template<int EPI>
__global__ __launch_bounds__(256) void k_mgemm(const __hip_bfloat16* __restrict__ A,
    const __hip_bfloat16* __restrict__ Wt, const float* __restrict__ bias,
    const float* __restrict__ R, float* __restrict__ C, int M, int K, int ldc, int Nout){
  __shared__ short As[8192];   // [128 rows][64 k] bf16, slot-swizzled
  __shared__ short Bs[8192];
  int t = threadIdx.x, lane = t&63, wave = t>>6;
  int m0 = blockIdx.y*128, n0 = blockIdx.x*128;
  int wm = (wave>>1)*64, wn = (wave&1)*64;
  f32x4 acc[4][4] = {};
  // staging descriptors: LDS linear dest (base+lane*16), pre-swizzled global src
  int soff[4], srow[4], scol[4];
#pragma unroll
  for(int c=0;c<4;c++){
    int off = (wave*4+c)*1024 + lane*16;   // byte offset in 16KB tile
    int row = off>>7;                       // 128B per row
    int sl  = ((off>>4)&7) ^ (row&7);       // logical 16B slot for this phys slot
    soff[c]=off; srow[c]=row; scol[c]=sl*8;
  }
  for(int kt=0; kt<K; kt+=64){
#pragma unroll
    for(int c=0;c<4;c++){
      gload16(&A [(m0+srow[c])*K + kt + scol[c]], (char*)As + soff[c]);
      gload16(&Wt[(n0+srow[c])*K + kt + scol[c]], (char*)Bs + soff[c]);
    }
    asm volatile("s_waitcnt vmcnt(0)" ::: "memory");
    __syncthreads();
#pragma unroll
    for(int ks=0; ks<2; ks++){
      short8v a[4], b[4];
      int k8 = ks*4 + (lane>>4);
#pragma unroll
      for(int i=0;i<4;i++){
        int lr = wm + i*16 + (lane&15);
        a[i] = *(const short8v*)&As[lr*64 + (k8 ^ (lr&7))*8];
      }
#pragma unroll
      for(int j=0;j<4;j++){
        int lr = wn + j*16 + (lane&15);
        b[j] = *(const short8v*)&Bs[lr*64 + (k8 ^ (lr&7))*8];
      }
#pragma unroll
      for(int i=0;i<4;i++)
#pragma unroll
        for(int j=0;j<4;j++)
          acc[i][j] = __builtin_amdgcn_mfma_f32_16x16x32_bf16(a[i], b[j], acc[i][j], 0,0,0);
    }
    __syncthreads();
  }
#pragma unroll
  for(int i=0;i<4;i++){
    int grow0 = m0 + wm + i*16 + (lane>>4)*4;
#pragma unroll
    for(int j=0;j<4;j++){
      int gcol = n0 + wn + j*16 + (lane&15);
      if(gcol < Nout){
#pragma unroll
        for(int r=0;r<4;r++){
          float v = acc[i][j][r];
          int grow = grow0 + r;
          if(EPI==1) v += R[grow*ldc+gcol];
          if(EPI==2) v = gelu_f(v + bias[gcol]);
          if(EPI==3) v = softplus_f(v + bias[gcol]);
          C[grow*ldc+gcol] = v;
        }
      }
    }
  }
}

// ---- causal depthwise conv (k=4) + bias + silu; xin = xz[:, :512]
//      outputs xs (f32, for scan) and xs_bf (bf16, GEMM A-operand) ----
__global__ void k_conv(const float* __restrict__ xz, const float* __restrict__ cw,
                       const float* __restrict__ cb, float* __restrict__ xs,
                       __hip_bfloat16* __restrict__ xs_bf){
  int idx = blockIdx.x*blockDim.x + threadIdx.x; // L_SEQ*128 threads
  int l = idx>>7, c4 = (idx&127)*4;
  float acc[4];
#pragma unroll
  for(int j=0;j<4;j++) acc[j] = cb[c4+j];
#pragma unroll
  for(int k=0;k<4;k++){
    int ls = l-3+k;
    if(ls>=0){
      float4 xv = *(const float4*)&xz[ls*1024 + c4];
      acc[0] = fmaf(xv.x, cw[(c4+0)*4+k], acc[0]);
      acc[1] = fmaf(xv.y, cw[(c4+1)*4+k], acc[1]);
      acc[2] = fmaf(xv.z, cw[(c4+2)*4+k], acc[2]);
      acc[3] = fmaf(xv.w, cw[(c4+3)*4+k], acc[3]);
    }
  }
  float4 o = {silu_f(acc[0]),silu_f(acc[1]),silu_f(acc[2]),silu_f(acc[3])};
  *(float4*)&xs[l*DI + c4] = o;
  __hip_bfloat16 ob[4] = {__float2bfloat16(o.x),__float2bfloat16(o.y),
                          __float2bfloat16(o.z),__float2bfloat16(o.w)};
  *(uint2*)&xs_bf[l*DI + c4] = *(uint2*)ob;
}

// ---- scan phase 1 (thread-per-channel): per-chunk (prod dA, local carry) per state ----
__global__ __launch_bounds__(256) void k_scan1(const float* __restrict__ delta, const float* __restrict__ xs,
                        const float* __restrict__ dbc32, const float* __restrict__ A_log,
                        float* __restrict__ Atot, float* __restrict__ Btot){
  int t = threadIdx.x;
  int chunk = blockIdx.x >> 1;
  int e = ((blockIdx.x & 1) << 8) + t;
  float A[16];
  {
    const float4* al = (const float4*)&A_log[e*DS];
#pragma unroll
    for(int q=0;q<4;q++){
      float4 a = al[q];
      A[q*4+0] = -__expf(a.x); A[q*4+1] = -__expf(a.y);
      A[q*4+2] = -__expf(a.z); A[q*4+3] = -__expf(a.w);
    }
  }
  float carry[16], aprod[16];
#pragma unroll
  for(int n=0;n<16;n++){ carry[n]=0.f; aprod[n]=1.f; }
  int l0 = chunk*CHL;
#pragma unroll 2
  for(int l=l0; l<l0+CHL; l++){
    float d  = delta[l*DI+e];
    float xv = xs[l*DI+e];
    float dxv = d*xv;
    const float4* bp = (const float4*)&dbc32[l*32];
    float4 b0=bp[0], b1=bp[1], b2=bp[2], b3=bp[3];
    float B[16] = {b0.x,b0.y,b0.z,b0.w, b1.x,b1.y,b1.z,b1.w,
                   b2.x,b2.y,b2.z,b2.w, b3.x,b3.y,b3.z,b3.w};
#pragma unroll
    for(int n=0;n<16;n++){
      float dA = __expf(d*A[n]);
      carry[n] = fmaf(carry[n], dA, dxv*B[n]);
      aprod[n] *= dA;
    }
  }
  float4* ap = (float4*)&Atot[chunk*8192 + e*DS];
  float4* bp = (float4*)&Btot[chunk*8192 + e*DS];
#pragma unroll
  for(int q=0;q<4;q++){
    ap[q] = make_float4(aprod[q*4],aprod[q*4+1],aprod[q*4+2],aprod[q*4+3]);
    bp[q] = make_float4(carry[q*4],carry[q*4+1],carry[q*4+2],carry[q*4+3]);
  }
}

// ---- scan phase 2: carry-in per chunk (h0 may alias Btot: load-before-store) ----
__global__ void k_scan2(const float* __restrict__ Atot, const float* __restrict__ Btot,
                        float* __restrict__ h0){
  int tg = blockIdx.x*256 + threadIdx.x;
  float carry = 0.f;
  for(int c=0;c<NCH;c++){
    float a = Atot[c*8192+tg];
    float b = Btot[c*8192+tg];
    h0[c*8192+tg] = carry;
    carry = fmaf(carry, a, b);
  }
}

// ---- scan phase 3 (thread-per-channel): replay with carry-in,
//      fuse y = (sum_n h*C + xs*D) * silu(z), output bf16 ----
__global__ __launch_bounds__(256) void k_scan3(const float* __restrict__ delta, const float* __restrict__ xs,
                        const float* __restrict__ dbc32, const float* __restrict__ A_log,
                        const float* __restrict__ Dp, const float* __restrict__ h0,
                        const float* __restrict__ xz, __hip_bfloat16* __restrict__ y){
  int t = threadIdx.x;
  int chunk = blockIdx.x >> 1;
  int e = ((blockIdx.x & 1) << 8) + t;
  float A[16];
  {
    const float4* al = (const float4*)&A_log[e*DS];
#pragma unroll
    for(int q=0;q<4;q++){
      float4 a = al[q];
      A[q*4+0] = -__expf(a.x); A[q*4+1] = -__expf(a.y);
      A[q*4+2] = -__expf(a.z); A[q*4+3] = -__expf(a.w);
    }
  }
  float carry[16];
  {
    const float4* hp = (const float4*)&h0[chunk*8192 + e*DS];
#pragma unroll
    for(int q=0;q<4;q++){
      float4 h = hp[q];
      carry[q*4+0]=h.x; carry[q*4+1]=h.y; carry[q*4+2]=h.z; carry[q*4+3]=h.w;
    }
  }
  float Dv = Dp[e];
  int l0 = chunk*CHL;
#pragma unroll 2
  for(int l=l0; l<l0+CHL; l++){
    float d  = delta[l*DI+e];
    float xv = xs[l*DI+e];
    float dxv = d*xv;
    const float4* bp = (const float4*)&dbc32[l*32];
    float4 b0=bp[0], b1=bp[1], b2=bp[2], b3=bp[3];
    float4 c0=bp[4], c1=bp[5], c2=bp[6], c3=bp[7];
    float B[16] = {b0.x,b0.y,b0.z,b0.w, b1.x,b1.y,b1.z,b1.w,
                   b2.x,b2.y,b2.z,b2.w, b3.x,b3.y,b3.z,b3.w};
    float Cv[16] = {c0.x,c0.y,c0.z,c0.w, c1.x,c1.y,c1.z,c1.w,
                    c2.x,c2.y,c2.z,c2.w, c3.x,c3.y,c3.z,c3.w};
    float p[4] = {0.f,0.f,0.f,0.f};
#pragma unroll
    for(int n=0;n<16;n++){
      float dA = __expf(d*A[n]);
      carry[n] = fmaf(carry[n], dA, dxv*B[n]);
      p[n&3] = fmaf(carry[n], Cv[n], p[n&3]);
    }
    float ps = (p[0]+p[1]) + (p[2]+p[3]);
    float z = xz[l*1024 + 512 + e];
    y[l*DI+e] = __float2bfloat16(fmaf(xv, Dv, ps) * silu_f(z));
  }
}

// ---- final: LN(128) -> @W2(128,1)+b2 -> tanh, one wave per row ----
__global__ void k_final(const float* __restrict__ h2, const float* __restrict__ g,
                        const float* __restrict__ b, const float* __restrict__ W2,
                        const float* __restrict__ b2, float* __restrict__ out){
  int lane = threadIdx.x&63;
  int wv = threadIdx.x>>6;
  int r = blockIdx.x*4 + wv;
  float v0 = h2[r*128+lane], v1 = h2[r*128+64+lane];
  float s = v0+v1, sq = v0*v0+v1*v1;
#pragma unroll
  for(int o=32;o;o>>=1){ s += __shfl_xor(s,o); sq += __shfl_xor(sq,o); }
  float mean = s*(1.0f/128), var = sq*(1.0f/128) - mean*mean;
  float rs = rsqrtf(var+1e-5f);
  float n0 = (v0-mean)*rs*g[lane]+b[lane];
  float n1 = (v1-mean)*rs*g[lane+64]+b[lane+64];
  float d = n0*W2[lane] + n1*W2[lane+64];
#pragma unroll
  for(int o=32;o;o>>=1) d += __shfl_xor(d,o);
  if(lane==0) out[r] = tanhf(d + b2[0]);
}

extern "C" void kernel_launch(void* const* d_in, const int* in_sizes, int n_in,
                              void* d_out, int out_size, void* d_ws, size_t ws_size,
                              hipStream_t stream){
  const float* x    = (const float*)d_in[0];
  const float* Win  = (const float*)d_in[1];
  const float* bin  = (const float*)d_in[2];
  const float* ln1g = (const float*)d_in[3];
  const float* ln1b = (const float*)d_in[4];
  const float* rmsw = (const float*)d_in[5];
  const float* inW  = (const float*)d_in[6];
  const float* convW= (const float*)d_in[7];
  const float* convB= (const float*)d_in[8];
  const float* xpW  = (const float*)d_in[9];
  const float* dtW  = (const float*)d_in[10];
  const float* dtB  = (const float*)d_in[11];
  const float* A_log= (const float*)d_in[12];
  const float* Dp   = (const float*)d_in[13];
  const float* outW = (const float*)d_in[14];
  const float* ln2g = (const float*)d_in[15];
  const float* ln2b = (const float*)d_in[16];
  const float* W1   = (const float*)d_in[17];
  const float* b1   = (const float*)d_in[18];
  const float* ln3g = (const float*)d_in[19];
  const float* ln3b = (const float*)d_in[20];
  const float* W2   = (const float*)d_in[21];
  const float* b2   = (const float*)d_in[22];
  float* out = (float*)d_out;
  float* ws = (float*)d_ws;
  float* u     = ws;                    // 16384*256 f32
  __hip_bfloat16* hn_bf = (__hip_bfloat16*)(ws + 4194304);   // 16384*256 bf16
  float* xz    = ws + 8388608;          // 16384*1024 f32
  float* xs    = ws + 25165824;         // 16384*512 f32
  float* dbc32 = ws + 33554432;         // 16384*32 f32
  float* delta = ws + 34340864;         // 16384*512 f32
  __hip_bfloat16* y_bf  = (__hip_bfloat16*)(ws + 42729472);  // 16384*512 bf16
  __hip_bfloat16* xs_bf = (__hip_bfloat16*)(ws + 46923776);  // 16384*512 bf16
  float* Atot  = ws + 51118080;         // NCH*8192
  float* Btot  = ws + 53215232;         // NCH*8192
  float* h0    = Btot;                  // aliased (scan2 loads before store)
  float* h2    = u;                     // aliased (u dead after k_ln)
  __hip_bfloat16* inWt  = (__hip_bfloat16*)(ws + 55312384);  // 2*1024*256 bf16
  __hip_bfloat16* outWt = (__hip_bfloat16*)(ws + 55574528);  // 2*256*512 bf16
  __hip_bfloat16* W1t   = (__hip_bfloat16*)(ws + 55705600);  // 128*256 bf16
  __hip_bfloat16* Wd_t  = (__hip_bfloat16*)(ws + 55721984);  // 2*512*512 bf16
  __hip_bfloat16* Wbc_t = (__hip_bfloat16*)(ws + 55984128);  // 2*128*512 bf16

  k_cvtw<<<3200,256,0,stream>>>(inW, outW, W1, inWt, outWt, W1t);
  k_wd<<<2560,256,0,stream>>>(xpW, dtW, Wd_t, Wbc_t);
  k_input<<<L_SEQ,256,0,stream>>>(x,Win,bin,ln1g,ln1b,u);
  for(int i=0;i<2;i++){
    k_rms<<<L_SEQ,256,0,stream>>>(u, rmsw+i*DM, hn_bf);
    k_mgemm<0><<<dim3(8, L_SEQ/128),256,0,stream>>>(hn_bf, inWt+i*262144, nullptr, nullptr, xz, L_SEQ, DM, 1024, 1024);
    k_conv<<<L_SEQ*128/256,256,0,stream>>>(xz, convW+i*DI*4, convB+i*DI, xs, xs_bf);
    k_mgemm<3><<<dim3(4, L_SEQ/128),256,0,stream>>>(xs_bf, Wd_t+i*262144, dtB+i*DI, nullptr, delta, L_SEQ, DI, 512, 512);
    k_mgemm<0><<<dim3(1, L_SEQ/128),256,0,stream>>>(xs_bf, Wbc_t+i*65536, nullptr, nullptr, dbc32, L_SEQ, DI, 32, 32);
    k_scan1<<<NCH*2,256,0,stream>>>(delta, xs, dbc32, A_log+i*DI*DS, Atot, Btot);
    k_scan2<<<32,256,0,stream>>>(Atot, Btot, h0);
    k_scan3<<<NCH*2,256,0,stream>>>(delta, xs, dbc32, A_log+i*DI*DS, Dp+i*DI, h0, xz, y_bf);
    k_mgemm<1><<<dim3(2, L_SEQ/128),256,0,stream>>>(y_bf, outWt+i*131072, nullptr, u, u, L_SEQ, DI, 256, 256);
  }
  k_ln<<<L_SEQ,256,0,stream>>>(u, ln2g, ln2b, hn_bf);
  k_mgemm<2><<<dim3(1, L_SEQ/128),256,0,stream>>>(hn_bf, W1t, b1, nullptr, h2, L_SEQ, DM, 128, 128);
  k_final<<<L_SEQ/4,256,0,stream>>>(h2, ln3g, ln3b, W2, b2, out);
}

// Round 5
// 535.434 us; speedup vs baseline: 2.2899x; 1.1656x over previous
//
#include <hip/hip_runtime.h>
#include <hip/hip_bf16.h>
#include <math.h>

#define L_SEQ 16384
#define DM 256
#define DI 512
#define DS 16
#define NCH 256   // number of scan chunks
#define CHL 64    // chunk length (NCH*CHL == L_SEQ)
#define CLB 32    // conv: timesteps per thread

typedef __attribute__((ext_vector_type(8))) short short8v;
typedef __attribute__((ext_vector_type(4))) float f32x4;

__device__ __forceinline__ float warpSum(float v){
#pragma unroll
  for(int o=32;o;o>>=1) v += __shfl_xor(v,o);
  return v;
}
__device__ __forceinline__ float gelu_f(float x){
  float x3 = x*x*x;
  return 0.5f*x*(1.0f + tanhf(0.7978845608028654f*(x + 0.044715f*x3)));
}
__device__ __forceinline__ float silu_f(float x){
  return x / (1.0f + __expf(-x));
}
__device__ __forceinline__ float softplus_f(float x){
  return fmaxf(x,0.0f) + log1pf(__expf(-fabsf(x)));
}
__device__ __forceinline__ float bf2f(unsigned short u){
  return __uint_as_float(((unsigned int)u)<<16);
}
__device__ __forceinline__ void gload16(const void* g, void* l){
  __builtin_amdgcn_global_load_lds((const __attribute__((address_space(1))) void*)g,
                                   (__attribute__((address_space(3))) void*)l, 16, 0, 0);
}
__device__ __forceinline__ void stv(float* p, float v){ *p = v; }
__device__ __forceinline__ void stv(__hip_bfloat16* p, float v){ *p = __float2bfloat16(v); }

// ---- weight convert + transpose to bf16: Wt[n][k] = bf16(W[k][n]) ----
__global__ void k_cvtw(const float* __restrict__ inW, const float* __restrict__ outW,
                       const float* __restrict__ W1, __hip_bfloat16* __restrict__ inWt,
                       __hip_bfloat16* __restrict__ outWt, __hip_bfloat16* __restrict__ W1t){
  int idx = blockIdx.x*256 + threadIdx.x;
  if(idx < 524288){                      // inW: 2 layers of [256][1024] -> [1024][256]
    int layer = idx >> 18;
    int r = idx & 262143;
    int n = r >> 8, k = r & 255;
    inWt[idx] = __float2bfloat16(inW[layer*262144 + k*1024 + n]);
  } else if(idx < 786432){               // outW: 2 layers of [512][256] -> [256][512]
    int j = idx - 524288;
    int layer = j >> 17;
    int r = j & 131071;
    int n = r >> 9, k = r & 511;
    outWt[j] = __float2bfloat16(outW[layer*131072 + k*256 + n]);
  } else if(idx < 819200){               // W1: [256][128] -> [128][256]
    int j = idx - 786432;
    int n = j >> 8, k = j & 255;
    W1t[j] = __float2bfloat16(W1[k*128 + n]);
  }
}

// ---- fold xpW/dtW: Wd_t[layer][n][k] = sum_j xpW[k][j]*dtW[j][n] (delta pre-act),
//      Wbc_t[layer][n][k] = xpW[k][16+n] for n<32, 0 pad to 128 rows ----
__global__ void k_wd(const float* __restrict__ xpW, const float* __restrict__ dtW,
                     __hip_bfloat16* __restrict__ Wd_t, __hip_bfloat16* __restrict__ Wbc_t){
  int idx = blockIdx.x*256 + threadIdx.x;
  if(idx < 524288){                      // 2 layers x [512 n][512 k]
    int layer = idx >> 18;
    int r = idx & 262143;
    int n = r >> 9, k = r & 511;
    const float* xp = xpW + layer*512*48;
    const float* dt = dtW + layer*16*512;
    float s = 0.f;
#pragma unroll
    for(int j=0;j<16;j++) s = fmaf(xp[k*48+j], dt[j*512+n], s);
    Wd_t[idx] = __float2bfloat16(s);
  } else if(idx < 655360){               // 2 layers x [128 n][512 k]
    int j2 = idx - 524288;
    int layer = j2 >> 16;
    int r = j2 & 65535;
    int n = r >> 9, k = r & 511;
    float v = (n < 32) ? xpW[layer*512*48 + k*48 + 16 + n] : 0.f;
    Wbc_t[j2] = __float2bfloat16(v);
  }
}

// ---- input projection + LN + gelu: u = gelu(LN(x@Win + bin)) ----
__global__ void k_input(const float* __restrict__ x, const float* __restrict__ Win,
                        const float* __restrict__ bin, const float* __restrict__ g,
                        const float* __restrict__ b, float* __restrict__ u){
  int r = blockIdx.x, t = threadIdx.x;
  __shared__ float xr[32];
  __shared__ float sA[4], sB[4];
  if(t<32) xr[t] = x[r*32+t];
  __syncthreads();
  float v = bin[t];
#pragma unroll
  for(int k=0;k<32;k++) v = fmaf(xr[k], Win[k*DM+t], v);
  float s = warpSum(v), sq = warpSum(v*v);
  if((t&63)==0){ sA[t>>6]=s; sB[t>>6]=sq; }
  __syncthreads();
  float mean = (sA[0]+sA[1]+sA[2]+sA[3])*(1.0f/DM);
  float msq  = (sB[0]+sB[1]+sB[2]+sB[3])*(1.0f/DM);
  float var = msq - mean*mean;
  float nv = (v-mean)*rsqrtf(var+1e-5f)*g[t]+b[t];
  u[r*DM+t] = gelu_f(nv);
}

// ---- rmsnorm over 256 -> bf16 ----
__global__ void k_rms(const float* __restrict__ u, const float* __restrict__ w,
                      __hip_bfloat16* __restrict__ o){
  int r=blockIdx.x, t=threadIdx.x;
  __shared__ float sA[4];
  float v = u[r*DM+t];
  float sq = warpSum(v*v);
  if((t&63)==0) sA[t>>6]=sq;
  __syncthreads();
  float ms = (sA[0]+sA[1]+sA[2]+sA[3])*(1.0f/DM);
  o[r*DM+t] = __float2bfloat16(v*rsqrtf(ms+1e-5f)*w[t]);
}

// ---- layernorm over 256 -> bf16 ----
__global__ void k_ln(const float* __restrict__ u, const float* __restrict__ g,
                     const float* __restrict__ b, __hip_bfloat16* __restrict__ o){
  int r=blockIdx.x, t=threadIdx.x;
  __shared__ float sA[4], sB[4];
  float v = u[r*DM+t];
  float s = warpSum(v), sq = warpSum(v*v);
  if((t&63)==0){ sA[t>>6]=s; sB[t>>6]=sq; }
  __syncthreads();
  float mean = (sA[0]+sA[1]+sA[2]+sA[3])*(1.0f/DM);
  float msq  = (sB[0]+sB[1]+sB[2]+sB[3])*(1.0f/DM);
  float var = msq - mean*mean;
  o[r*DM+t] = __float2bfloat16((v-mean)*rsqrtf(var+1e-5f)*g[t]+b[t]);
}

// ---- bf16 MFMA GEMM: C[M,:](OT, stride ldc) = A[M,K](bf16) @ Wt[N,K](bf16)^T
//      EPI: 0=store, 1=+R, 2=gelu(+bias), 3=softplus(+bias). Stores cols < Nout. ----
template<int EPI, typename OT>
__global__ __launch_bounds__(256) void k_mgemm(const __hip_bfloat16* __restrict__ A,
    const __hip_bfloat16* __restrict__ Wt, const float* __restrict__ bias,
    const float* __restrict__ R, OT* __restrict__ C, int M, int K, int ldc, int Nout){
  __shared__ short As[8192];   // [128 rows][64 k] bf16, slot-swizzled
  __shared__ short Bs[8192];
  int t = threadIdx.x, lane = t&63, wave = t>>6;
  int m0 = blockIdx.y*128, n0 = blockIdx.x*128;
  int wm = (wave>>1)*64, wn = (wave&1)*64;
  f32x4 acc[4][4] = {};
  // staging descriptors: LDS linear dest (base+lane*16), pre-swizzled global src
  int soff[4], srow[4], scol[4];
#pragma unroll
  for(int c=0;c<4;c++){
    int off = (wave*4+c)*1024 + lane*16;   // byte offset in 16KB tile
    int row = off>>7;                       // 128B per row
    int sl  = ((off>>4)&7) ^ (row&7);       // logical 16B slot for this phys slot
    soff[c]=off; srow[c]=row; scol[c]=sl*8;
  }
  for(int kt=0; kt<K; kt+=64){
#pragma unroll
    for(int c=0;c<4;c++){
      gload16(&A [(m0+srow[c])*K + kt + scol[c]], (char*)As + soff[c]);
      gload16(&Wt[(n0+srow[c])*K + kt + scol[c]], (char*)Bs + soff[c]);
    }
    asm volatile("s_waitcnt vmcnt(0)" ::: "memory");
    __syncthreads();
#pragma unroll
    for(int ks=0; ks<2; ks++){
      short8v a[4], b[4];
      int k8 = ks*4 + (lane>>4);
#pragma unroll
      for(int i=0;i<4;i++){
        int lr = wm + i*16 + (lane&15);
        a[i] = *(const short8v*)&As[lr*64 + (k8 ^ (lr&7))*8];
      }
#pragma unroll
      for(int j=0;j<4;j++){
        int lr = wn + j*16 + (lane&15);
        b[j] = *(const short8v*)&Bs[lr*64 + (k8 ^ (lr&7))*8];
      }
#pragma unroll
      for(int i=0;i<4;i++)
#pragma unroll
        for(int j=0;j<4;j++)
          acc[i][j] = __builtin_amdgcn_mfma_f32_16x16x32_bf16(a[i], b[j], acc[i][j], 0,0,0);
    }
    __syncthreads();
  }
#pragma unroll
  for(int i=0;i<4;i++){
    int grow0 = m0 + wm + i*16 + (lane>>4)*4;
#pragma unroll
    for(int j=0;j<4;j++){
      int gcol = n0 + wn + j*16 + (lane&15);
      if(gcol < Nout){
#pragma unroll
        for(int r=0;r<4;r++){
          float v = acc[i][j][r];
          int grow = grow0 + r;
          if(EPI==1) v += R[grow*ldc+gcol];
          if(EPI==2) v = gelu_f(v + bias[gcol]);
          if(EPI==3) v = softplus_f(v + bias[gcol]);
          stv(&C[grow*ldc+gcol], v);
        }
      }
    }
  }
}

// ---- causal depthwise conv (k=4) + bias + silu, sliding window.
//      xin = xz_bf[:, :512] (bf16); out xs_bf (bf16). Thread: 4 ch x CLB steps. ----
__global__ __launch_bounds__(256) void k_conv(const __hip_bfloat16* __restrict__ xz,
                       const float* __restrict__ cw, const float* __restrict__ cb,
                       __hip_bfloat16* __restrict__ xs_bf){
  int idx = blockIdx.x*256 + threadIdx.x;   // (L_SEQ/CLB)*128 threads
  int cg = idx & 127, lb = idx >> 7;
  int c4 = cg*4;
  int l0 = lb*CLB;
  float w[4][4], bias[4];
#pragma unroll
  for(int j=0;j<4;j++){
    float4 wv = *(const float4*)&cw[(c4+j)*4];
    w[j][0]=wv.x; w[j][1]=wv.y; w[j][2]=wv.z; w[j][3]=wv.w;
  }
  { float4 bv = *(const float4*)&cb[c4];
    bias[0]=bv.x; bias[1]=bv.y; bias[2]=bv.z; bias[3]=bv.w; }
  float xm0[4], xm1[4], xm2[4];   // x[l-3], x[l-2], x[l-1]
#pragma unroll
  for(int j=0;j<4;j++){ xm0[j]=0.f; xm1[j]=0.f; xm2[j]=0.f; }
  if(l0 >= 3){
    ushort4 r0 = *(const ushort4*)&xz[(l0-3)*1024 + c4];
    ushort4 r1 = *(const ushort4*)&xz[(l0-2)*1024 + c4];
    ushort4 r2 = *(const ushort4*)&xz[(l0-1)*1024 + c4];
    xm0[0]=bf2f(r0.x); xm0[1]=bf2f(r0.y); xm0[2]=bf2f(r0.z); xm0[3]=bf2f(r0.w);
    xm1[0]=bf2f(r1.x); xm1[1]=bf2f(r1.y); xm1[2]=bf2f(r1.z); xm1[3]=bf2f(r1.w);
    xm2[0]=bf2f(r2.x); xm2[1]=bf2f(r2.y); xm2[2]=bf2f(r2.z); xm2[3]=bf2f(r2.w);
  }
  for(int l=l0; l<l0+CLB; l++){
    ushort4 rc = *(const ushort4*)&xz[l*1024 + c4];
    float xc[4] = {bf2f(rc.x), bf2f(rc.y), bf2f(rc.z), bf2f(rc.w)};
    __hip_bfloat16 ob[4];
#pragma unroll
    for(int j=0;j<4;j++){
      float acc = bias[j];
      acc = fmaf(xm0[j], w[j][0], acc);
      acc = fmaf(xm1[j], w[j][1], acc);
      acc = fmaf(xm2[j], w[j][2], acc);
      acc = fmaf(xc[j],  w[j][3], acc);
      ob[j] = __float2bfloat16(silu_f(acc));
    }
    *(uint2*)&xs_bf[l*DI + c4] = *(uint2*)ob;
#pragma unroll
    for(int j=0;j<4;j++){ xm0[j]=xm1[j]; xm1[j]=xm2[j]; xm2[j]=xc[j]; }
  }
}

// ---- scan phase 1 (thread-per-channel): per-chunk (prod dA, local carry) per state ----
__global__ __launch_bounds__(256) void k_scan1(const float* __restrict__ delta,
                        const __hip_bfloat16* __restrict__ xs,
                        const float* __restrict__ dbc32, const float* __restrict__ A_log,
                        float* __restrict__ Atot, float* __restrict__ Btot){
  int t = threadIdx.x;
  int chunk = blockIdx.x >> 1;
  int e = ((blockIdx.x & 1) << 8) + t;
  float A[16];
  {
    const float4* al = (const float4*)&A_log[e*DS];
#pragma unroll
    for(int q=0;q<4;q++){
      float4 a = al[q];
      A[q*4+0] = -__expf(a.x); A[q*4+1] = -__expf(a.y);
      A[q*4+2] = -__expf(a.z); A[q*4+3] = -__expf(a.w);
    }
  }
  float carry[16], aprod[16];
#pragma unroll
  for(int n=0;n<16;n++){ carry[n]=0.f; aprod[n]=1.f; }
  int l0 = chunk*CHL;
#pragma unroll 2
  for(int l=l0; l<l0+CHL; l++){
    float d  = delta[l*DI+e];
    float xv = bf2f(*(const unsigned short*)&xs[l*DI+e]);
    float dxv = d*xv;
    const float4* bp = (const float4*)&dbc32[l*32];
    float4 b0=bp[0], b1=bp[1], b2=bp[2], b3=bp[3];
    float B[16] = {b0.x,b0.y,b0.z,b0.w, b1.x,b1.y,b1.z,b1.w,
                   b2.x,b2.y,b2.z,b2.w, b3.x,b3.y,b3.z,b3.w};
#pragma unroll
    for(int n=0;n<16;n++){
      float dA = __expf(d*A[n]);
      carry[n] = fmaf(carry[n], dA, dxv*B[n]);
      aprod[n] *= dA;
    }
  }
  float4* ap = (float4*)&Atot[chunk*8192 + e*DS];
  float4* bp = (float4*)&Btot[chunk*8192 + e*DS];
#pragma unroll
  for(int q=0;q<4;q++){
    ap[q] = make_float4(aprod[q*4],aprod[q*4+1],aprod[q*4+2],aprod[q*4+3]);
    bp[q] = make_float4(carry[q*4],carry[q*4+1],carry[q*4+2],carry[q*4+3]);
  }
}

// ---- scan phase 2: carry-in per chunk (h0 may alias Btot: load-before-store) ----
__global__ void k_scan2(const float* __restrict__ Atot, const float* __restrict__ Btot,
                        float* __restrict__ h0){
  int tg = blockIdx.x*256 + threadIdx.x;
  float carry = 0.f;
  for(int c=0;c<NCH;c++){
    float a = Atot[c*8192+tg];
    float b = Btot[c*8192+tg];
    h0[c*8192+tg] = carry;
    carry = fmaf(carry, a, b);
  }
}

// ---- scan phase 3 (thread-per-channel): replay with carry-in,
//      fuse y = (sum_n h*C + xs*D) * silu(z), output bf16 ----
__global__ __launch_bounds__(256) void k_scan3(const float* __restrict__ delta,
                        const __hip_bfloat16* __restrict__ xs,
                        const float* __restrict__ dbc32, const float* __restrict__ A_log,
                        const float* __restrict__ Dp, const float* __restrict__ h0,
                        const __hip_bfloat16* __restrict__ xz, __hip_bfloat16* __restrict__ y){
  int t = threadIdx.x;
  int chunk = blockIdx.x >> 1;
  int e = ((blockIdx.x & 1) << 8) + t;
  float A[16];
  {
    const float4* al = (const float4*)&A_log[e*DS];
#pragma unroll
    for(int q=0;q<4;q++){
      float4 a = al[q];
      A[q*4+0] = -__expf(a.x); A[q*4+1] = -__expf(a.y);
      A[q*4+2] = -__expf(a.z); A[q*4+3] = -__expf(a.w);
    }
  }
  float carry[16];
  {
    const float4* hp = (const float4*)&h0[chunk*8192 + e*DS];
#pragma unroll
    for(int q=0;q<4;q++){
      float4 h = hp[q];
      carry[q*4+0]=h.x; carry[q*4+1]=h.y; carry[q*4+2]=h.z; carry[q*4+3]=h.w;
    }
  }
  float Dv = Dp[e];
  int l0 = chunk*CHL;
#pragma unroll 2
  for(int l=l0; l<l0+CHL; l++){
    float d  = delta[l*DI+e];
    float xv = bf2f(*(const unsigned short*)&xs[l*DI+e]);
    float dxv = d*xv;
    const float4* bp = (const float4*)&dbc32[l*32];
    float4 b0=bp[0], b1=bp[1], b2=bp[2], b3=bp[3];
    float4 c0=bp[4], c1=bp[5], c2=bp[6], c3=bp[7];
    float B[16] = {b0.x,b0.y,b0.z,b0.w, b1.x,b1.y,b1.z,b1.w,
                   b2.x,b2.y,b2.z,b2.w, b3.x,b3.y,b3.z,b3.w};
    float Cv[16] = {c0.x,c0.y,c0.z,c0.w, c1.x,c1.y,c1.z,c1.w,
                    c2.x,c2.y,c2.z,c2.w, c3.x,c3.y,c3.z,c3.w};
    float p[4] = {0.f,0.f,0.f,0.f};
#pragma unroll
    for(int n=0;n<16;n++){
      float dA = __expf(d*A[n]);
      carry[n] = fmaf(carry[n], dA, dxv*B[n]);
      p[n&3] = fmaf(carry[n], Cv[n], p[n&3]);
    }
    float ps = (p[0]+p[1]) + (p[2]+p[3]);
    float z = bf2f(*(const unsigned short*)&xz[l*1024 + 512 + e]);
    y[l*DI+e] = __float2bfloat16(fmaf(xv, Dv, ps) * silu_f(z));
  }
}

// ---- final: LN(128) -> @W2(128,1)+b2 -> tanh, one wave per row ----
__global__ void k_final(const float* __restrict__ h2, const float* __restrict__ g,
                        const float* __restrict__ b, const float* __restrict__ W2,
                        const float* __restrict__ b2, float* __restrict__ out){
  int lane = threadIdx.x&63;
  int wv = threadIdx.x>>6;
  int r = blockIdx.x*4 + wv;
  float v0 = h2[r*128+lane], v1 = h2[r*128+64+lane];
  float s = v0+v1, sq = v0*v0+v1*v1;
#pragma unroll
  for(int o=32;o;o>>=1){ s += __shfl_xor(s,o); sq += __shfl_xor(sq,o); }
  float mean = s*(1.0f/128), var = sq*(1.0f/128) - mean*mean;
  float rs = rsqrtf(var+1e-5f);
  float n0 = (v0-mean)*rs*g[lane]+b[lane];
  float n1 = (v1-mean)*rs*g[lane+64]+b[lane+64];
  float d = n0*W2[lane] + n1*W2[lane+64];
#pragma unroll
  for(int o=32;o;o>>=1) d += __shfl_xor(d,o);
  if(lane==0) out[r] = tanhf(d + b2[0]);
}

extern "C" void kernel_launch(void* const* d_in, const int* in_sizes, int n_in,
                              void* d_out, int out_size, void* d_ws, size_t ws_size,
                              hipStream_t stream){
  const float* x    = (const float*)d_in[0];
  const float* Win  = (const float*)d_in[1];
  const float* bin  = (const float*)d_in[2];
  const float* ln1g = (const float*)d_in[3];
  const float* ln1b = (const float*)d_in[4];
  const float* rmsw = (const float*)d_in[5];
  const float* inW  = (const float*)d_in[6];
  const float* convW= (const float*)d_in[7];
  const float* convB= (const float*)d_in[8];
  const float* xpW  = (const float*)d_in[9];
  const float* dtW  = (const float*)d_in[10];
  const float* dtB  = (const float*)d_in[11];
  const float* A_log= (const float*)d_in[12];
  const float* Dp   = (const float*)d_in[13];
  const float* outW = (const float*)d_in[14];
  const float* ln2g = (const float*)d_in[15];
  const float* ln2b = (const float*)d_in[16];
  const float* W1   = (const float*)d_in[17];
  const float* b1   = (const float*)d_in[18];
  const float* ln3g = (const float*)d_in[19];
  const float* ln3b = (const float*)d_in[20];
  const float* W2   = (const float*)d_in[21];
  const float* b2   = (const float*)d_in[22];
  float* out = (float*)d_out;
  float* ws = (float*)d_ws;
  float* u     = ws;                    // 16384*256 f32
  __hip_bfloat16* hn_bf = (__hip_bfloat16*)(ws + 4194304);   // 16384*256 bf16
  __hip_bfloat16* xz_bf = (__hip_bfloat16*)(ws + 8388608);   // 16384*1024 bf16
  float* dbc32 = ws + 33554432;         // 16384*32 f32
  float* delta = ws + 34340864;         // 16384*512 f32
  __hip_bfloat16* y_bf  = (__hip_bfloat16*)(ws + 42729472);  // 16384*512 bf16
  __hip_bfloat16* xs_bf = (__hip_bfloat16*)(ws + 46923776);  // 16384*512 bf16
  float* Atot  = ws + 51118080;         // NCH*8192
  float* Btot  = ws + 53215232;         // NCH*8192
  float* h0    = Btot;                  // aliased (scan2 loads before store)
  float* h2    = u;                     // aliased (u dead after k_ln)
  __hip_bfloat16* inWt  = (__hip_bfloat16*)(ws + 55312384);  // 2*1024*256 bf16
  __hip_bfloat16* outWt = (__hip_bfloat16*)(ws + 55574528);  // 2*256*512 bf16
  __hip_bfloat16* W1t   = (__hip_bfloat16*)(ws + 55705600);  // 128*256 bf16
  __hip_bfloat16* Wd_t  = (__hip_bfloat16*)(ws + 55721984);  // 2*512*512 bf16
  __hip_bfloat16* Wbc_t = (__hip_bfloat16*)(ws + 55984128);  // 2*128*512 bf16

  k_cvtw<<<3200,256,0,stream>>>(inW, outW, W1, inWt, outWt, W1t);
  k_wd<<<2560,256,0,stream>>>(xpW, dtW, Wd_t, Wbc_t);
  k_input<<<L_SEQ,256,0,stream>>>(x,Win,bin,ln1g,ln1b,u);
  for(int i=0;i<2;i++){
    k_rms<<<L_SEQ,256,0,stream>>>(u, rmsw+i*DM, hn_bf);
    k_mgemm<0,__hip_bfloat16><<<dim3(8, L_SEQ/128),256,0,stream>>>(hn_bf, inWt+i*262144, nullptr, nullptr, xz_bf, L_SEQ, DM, 1024, 1024);
    k_conv<<<(L_SEQ/CLB)*128/256,256,0,stream>>>(xz_bf, convW+i*DI*4, convB+i*DI, xs_bf);
    k_mgemm<3,float><<<dim3(4, L_SEQ/128),256,0,stream>>>(xs_bf, Wd_t+i*262144, dtB+i*DI, nullptr, delta, L_SEQ, DI, 512, 512);
    k_mgemm<0,float><<<dim3(1, L_SEQ/128),256,0,stream>>>(xs_bf, Wbc_t+i*65536, nullptr, nullptr, dbc32, L_SEQ, DI, 32, 32);
    k_scan1<<<NCH*2,256,0,stream>>>(delta, xs_bf, dbc32, A_log+i*DI*DS, Atot, Btot);
    k_scan2<<<32,256,0,stream>>>(Atot, Btot, h0);
    k_scan3<<<NCH*2,256,0,stream>>>(delta, xs_bf, dbc32, A_log+i*DI*DS, Dp+i*DI, h0, xz_bf, y_bf);
    k_mgemm<1,float><<<dim3(2, L_SEQ/128),256,0,stream>>>(y_bf, outWt+i*131072, nullptr, u, u, L_SEQ, DI, 256, 256);
  }
  k_ln<<<L_SEQ,256,0,stream>>>(u, ln2g, ln2b, hn_bf);
  k_mgemm<2,float><<<dim3(1, L_SEQ/128),256,0,stream>>>(hn_bf, W1t, b1, nullptr, h2, L_SEQ, DM, 128, 128);
  k_final<<<L_SEQ/4,256,0,stream>>>(h2, ln3g, ln3b, W2, b2, out);
}

// Round 6
// 519.483 us; speedup vs baseline: 2.3602x; 1.0307x over previous
//
#include <hip/hip_runtime.h>
#include <hip/hip_bf16.h>
#include <math.h>

#define L_SEQ 16384
#define DM 256
#define DI 512
#define DS 16
#define NCH 512   // number of scan chunks
#define CHL 32    // chunk length (NCH*CHL == L_SEQ)
#define CLB 16    // conv: timesteps per thread

typedef __attribute__((ext_vector_type(8))) short short8v;
typedef __attribute__((ext_vector_type(4))) float f32x4;

__device__ __forceinline__ float warpSum(float v){
#pragma unroll
  for(int o=32;o;o>>=1) v += __shfl_xor(v,o);
  return v;
}
__device__ __forceinline__ float gelu_f(float x){
  float x3 = x*x*x;
  return 0.5f*x*(1.0f + tanhf(0.7978845608028654f*(x + 0.044715f*x3)));
}
__device__ __forceinline__ float silu_f(float x){
  return x / (1.0f + __expf(-x));
}
__device__ __forceinline__ float softplus_f(float x){
  return fmaxf(x,0.0f) + log1pf(__expf(-fabsf(x)));
}
__device__ __forceinline__ float bf2f(unsigned short u){
  return __uint_as_float(((unsigned int)u)<<16);
}
__device__ __forceinline__ void gload16(const void* g, void* l){
  __builtin_amdgcn_global_load_lds((const __attribute__((address_space(1))) void*)g,
                                   (__attribute__((address_space(3))) void*)l, 16, 0, 0);
}
__device__ __forceinline__ void stv(float* p, float v){ *p = v; }
__device__ __forceinline__ void stv(__hip_bfloat16* p, float v){ *p = __float2bfloat16(v); }

// ---- weight convert + transpose to bf16: Wt[n][k] = bf16(W[k][n]) ----
__global__ void k_cvtw(const float* __restrict__ inW, const float* __restrict__ outW,
                       const float* __restrict__ W1, __hip_bfloat16* __restrict__ inWt,
                       __hip_bfloat16* __restrict__ outWt, __hip_bfloat16* __restrict__ W1t){
  int idx = blockIdx.x*256 + threadIdx.x;
  if(idx < 524288){                      // inW: 2 layers of [256][1024] -> [1024][256]
    int layer = idx >> 18;
    int r = idx & 262143;
    int n = r >> 8, k = r & 255;
    inWt[idx] = __float2bfloat16(inW[layer*262144 + k*1024 + n]);
  } else if(idx < 786432){               // outW: 2 layers of [512][256] -> [256][512]
    int j = idx - 524288;
    int layer = j >> 17;
    int r = j & 131071;
    int n = r >> 9, k = r & 511;
    outWt[j] = __float2bfloat16(outW[layer*131072 + k*256 + n]);
  } else if(idx < 819200){               // W1: [256][128] -> [128][256]
    int j = idx - 786432;
    int n = j >> 8, k = j & 255;
    W1t[j] = __float2bfloat16(W1[k*128 + n]);
  }
}

// ---- fold xpW/dtW: Wd_t[layer][n][k] = sum_j xpW[k][j]*dtW[j][n] (delta pre-act),
//      Wbc_t[layer][n][k] = xpW[k][16+n] for n<32, 0 pad to 128 rows ----
__global__ void k_wd(const float* __restrict__ xpW, const float* __restrict__ dtW,
                     __hip_bfloat16* __restrict__ Wd_t, __hip_bfloat16* __restrict__ Wbc_t){
  int idx = blockIdx.x*256 + threadIdx.x;
  if(idx < 524288){                      // 2 layers x [512 n][512 k]
    int layer = idx >> 18;
    int r = idx & 262143;
    int n = r >> 9, k = r & 511;
    const float* xp = xpW + layer*512*48;
    const float* dt = dtW + layer*16*512;
    float s = 0.f;
#pragma unroll
    for(int j=0;j<16;j++) s = fmaf(xp[k*48+j], dt[j*512+n], s);
    Wd_t[idx] = __float2bfloat16(s);
  } else if(idx < 655360){               // 2 layers x [128 n][512 k]
    int j2 = idx - 524288;
    int layer = j2 >> 16;
    int r = j2 & 65535;
    int n = r >> 9, k = r & 511;
    float v = (n < 32) ? xpW[layer*512*48 + k*48 + 16 + n] : 0.f;
    Wbc_t[j2] = __float2bfloat16(v);
  }
}

// ---- input projection + LN + gelu: u = gelu(LN(x@Win + bin)) ----
__global__ void k_input(const float* __restrict__ x, const float* __restrict__ Win,
                        const float* __restrict__ bin, const float* __restrict__ g,
                        const float* __restrict__ b, float* __restrict__ u){
  int r = blockIdx.x, t = threadIdx.x;
  __shared__ float xr[32];
  __shared__ float sA[4], sB[4];
  if(t<32) xr[t] = x[r*32+t];
  __syncthreads();
  float v = bin[t];
#pragma unroll
  for(int k=0;k<32;k++) v = fmaf(xr[k], Win[k*DM+t], v);
  float s = warpSum(v), sq = warpSum(v*v);
  if((t&63)==0){ sA[t>>6]=s; sB[t>>6]=sq; }
  __syncthreads();
  float mean = (sA[0]+sA[1]+sA[2]+sA[3])*(1.0f/DM);
  float msq  = (sB[0]+sB[1]+sB[2]+sB[3])*(1.0f/DM);
  float var = msq - mean*mean;
  float nv = (v-mean)*rsqrtf(var+1e-5f)*g[t]+b[t];
  u[r*DM+t] = gelu_f(nv);
}

// ---- rmsnorm over 256 -> bf16 ----
__global__ void k_rms(const float* __restrict__ u, const float* __restrict__ w,
                      __hip_bfloat16* __restrict__ o){
  int r=blockIdx.x, t=threadIdx.x;
  __shared__ float sA[4];
  float v = u[r*DM+t];
  float sq = warpSum(v*v);
  if((t&63)==0) sA[t>>6]=sq;
  __syncthreads();
  float ms = (sA[0]+sA[1]+sA[2]+sA[3])*(1.0f/DM);
  o[r*DM+t] = __float2bfloat16(v*rsqrtf(ms+1e-5f)*w[t]);
}

// ---- layernorm over 256 -> bf16 ----
__global__ void k_ln(const float* __restrict__ u, const float* __restrict__ g,
                     const float* __restrict__ b, __hip_bfloat16* __restrict__ o){
  int r=blockIdx.x, t=threadIdx.x;
  __shared__ float sA[4], sB[4];
  float v = u[r*DM+t];
  float s = warpSum(v), sq = warpSum(v*v);
  if((t&63)==0){ sA[t>>6]=s; sB[t>>6]=sq; }
  __syncthreads();
  float mean = (sA[0]+sA[1]+sA[2]+sA[3])*(1.0f/DM);
  float msq  = (sB[0]+sB[1]+sB[2]+sB[3])*(1.0f/DM);
  float var = msq - mean*mean;
  o[r*DM+t] = __float2bfloat16((v-mean)*rsqrtf(var+1e-5f)*g[t]+b[t]);
}

// ---- bf16 MFMA GEMM: C[M,:](OT, stride ldc) = A[M,K](bf16) @ Wt[N,K](bf16)^T
//      EPI: 0=store, 1=+R, 2=gelu(+bias), 3=softplus(+bias). Stores cols < Nout. ----
template<int EPI, typename OT>
__global__ __launch_bounds__(256) void k_mgemm(const __hip_bfloat16* __restrict__ A,
    const __hip_bfloat16* __restrict__ Wt, const float* __restrict__ bias,
    const float* __restrict__ R, OT* __restrict__ C, int M, int K, int ldc, int Nout){
  __shared__ short As[8192];   // [128 rows][64 k] bf16, slot-swizzled
  __shared__ short Bs[8192];
  int t = threadIdx.x, lane = t&63, wave = t>>6;
  int m0 = blockIdx.y*128, n0 = blockIdx.x*128;
  int wm = (wave>>1)*64, wn = (wave&1)*64;
  f32x4 acc[4][4] = {};
  // staging descriptors: LDS linear dest (base+lane*16), pre-swizzled global src
  int soff[4], srow[4], scol[4];
#pragma unroll
  for(int c=0;c<4;c++){
    int off = (wave*4+c)*1024 + lane*16;   // byte offset in 16KB tile
    int row = off>>7;                       // 128B per row
    int sl  = ((off>>4)&7) ^ (row&7);       // logical 16B slot for this phys slot
    soff[c]=off; srow[c]=row; scol[c]=sl*8;
  }
  for(int kt=0; kt<K; kt+=64){
#pragma unroll
    for(int c=0;c<4;c++){
      gload16(&A [(m0+srow[c])*K + kt + scol[c]], (char*)As + soff[c]);
      gload16(&Wt[(n0+srow[c])*K + kt + scol[c]], (char*)Bs + soff[c]);
    }
    asm volatile("s_waitcnt vmcnt(0)" ::: "memory");
    __syncthreads();
#pragma unroll
    for(int ks=0; ks<2; ks++){
      short8v a[4], b[4];
      int k8 = ks*4 + (lane>>4);
#pragma unroll
      for(int i=0;i<4;i++){
        int lr = wm + i*16 + (lane&15);
        a[i] = *(const short8v*)&As[lr*64 + (k8 ^ (lr&7))*8];
      }
#pragma unroll
      for(int j=0;j<4;j++){
        int lr = wn + j*16 + (lane&15);
        b[j] = *(const short8v*)&Bs[lr*64 + (k8 ^ (lr&7))*8];
      }
#pragma unroll
      for(int i=0;i<4;i++)
#pragma unroll
        for(int j=0;j<4;j++)
          acc[i][j] = __builtin_amdgcn_mfma_f32_16x16x32_bf16(a[i], b[j], acc[i][j], 0,0,0);
    }
    __syncthreads();
  }
#pragma unroll
  for(int i=0;i<4;i++){
    int grow0 = m0 + wm + i*16 + (lane>>4)*4;
#pragma unroll
    for(int j=0;j<4;j++){
      int gcol = n0 + wn + j*16 + (lane&15);
      if(gcol < Nout){
#pragma unroll
        for(int r=0;r<4;r++){
          float v = acc[i][j][r];
          int grow = grow0 + r;
          if(EPI==1) v += R[grow*ldc+gcol];
          if(EPI==2) v = gelu_f(v + bias[gcol]);
          if(EPI==3) v = softplus_f(v + bias[gcol]);
          stv(&C[grow*ldc+gcol], v);
        }
      }
    }
  }
}

// ---- causal depthwise conv (k=4) + bias + silu, sliding window.
//      xin = xz_bf[:, :512] (bf16); out xs_bf (bf16). Thread: 4 ch x CLB steps. ----
__global__ __launch_bounds__(256) void k_conv(const __hip_bfloat16* __restrict__ xz,
                       const float* __restrict__ cw, const float* __restrict__ cb,
                       __hip_bfloat16* __restrict__ xs_bf){
  int idx = blockIdx.x*256 + threadIdx.x;   // (L_SEQ/CLB)*128 threads
  int cg = idx & 127, lb = idx >> 7;
  int c4 = cg*4;
  int l0 = lb*CLB;
  float w[4][4], bias[4];
#pragma unroll
  for(int j=0;j<4;j++){
    float4 wv = *(const float4*)&cw[(c4+j)*4];
    w[j][0]=wv.x; w[j][1]=wv.y; w[j][2]=wv.z; w[j][3]=wv.w;
  }
  { float4 bv = *(const float4*)&cb[c4];
    bias[0]=bv.x; bias[1]=bv.y; bias[2]=bv.z; bias[3]=bv.w; }
  float xm0[4], xm1[4], xm2[4];   // x[l-3], x[l-2], x[l-1]
#pragma unroll
  for(int j=0;j<4;j++){ xm0[j]=0.f; xm1[j]=0.f; xm2[j]=0.f; }
  if(l0 >= 3){
    ushort4 r0 = *(const ushort4*)&xz[(l0-3)*1024 + c4];
    ushort4 r1 = *(const ushort4*)&xz[(l0-2)*1024 + c4];
    ushort4 r2 = *(const ushort4*)&xz[(l0-1)*1024 + c4];
    xm0[0]=bf2f(r0.x); xm0[1]=bf2f(r0.y); xm0[2]=bf2f(r0.z); xm0[3]=bf2f(r0.w);
    xm1[0]=bf2f(r1.x); xm1[1]=bf2f(r1.y); xm1[2]=bf2f(r1.z); xm1[3]=bf2f(r1.w);
    xm2[0]=bf2f(r2.x); xm2[1]=bf2f(r2.y); xm2[2]=bf2f(r2.z); xm2[3]=bf2f(r2.w);
  }
  for(int l=l0; l<l0+CLB; l++){
    ushort4 rc = *(const ushort4*)&xz[l*1024 + c4];
    float xc[4] = {bf2f(rc.x), bf2f(rc.y), bf2f(rc.z), bf2f(rc.w)};
    __hip_bfloat16 ob[4];
#pragma unroll
    for(int j=0;j<4;j++){
      float acc = bias[j];
      acc = fmaf(xm0[j], w[j][0], acc);
      acc = fmaf(xm1[j], w[j][1], acc);
      acc = fmaf(xm2[j], w[j][2], acc);
      acc = fmaf(xc[j],  w[j][3], acc);
      ob[j] = __float2bfloat16(silu_f(acc));
    }
    *(uint2*)&xs_bf[l*DI + c4] = *(uint2*)ob;
#pragma unroll
    for(int j=0;j<4;j++){ xm0[j]=xm1[j]; xm1[j]=xm2[j]; xm2[j]=xc[j]; }
  }
}

// ---- scan phase 1 (thread-per-channel): per-chunk (prod dA, local carry) per state.
//      dbc chunk staged in LDS (uniform-address broadcast reads). ----
__global__ __launch_bounds__(256) void k_scan1(const float* __restrict__ delta,
                        const __hip_bfloat16* __restrict__ xs,
                        const float* __restrict__ dbc32, const float* __restrict__ A_log,
                        float* __restrict__ Atot, float* __restrict__ Btot){
  __shared__ float bcs[CHL*32];   // 4KB: [CHL][32] = B(16)|C(16) per step
  int t = threadIdx.x;
  int chunk = blockIdx.x >> 1;
  int e = ((blockIdx.x & 1) << 8) + t;
  int l0 = chunk*CHL;
  ((float4*)bcs)[t] = ((const float4*)&dbc32[l0*32])[t];   // CHL*32/4 == 256
  float A[16];
  {
    const float4* al = (const float4*)&A_log[e*DS];
#pragma unroll
    for(int q=0;q<4;q++){
      float4 a = al[q];
      A[q*4+0] = -__expf(a.x); A[q*4+1] = -__expf(a.y);
      A[q*4+2] = -__expf(a.z); A[q*4+3] = -__expf(a.w);
    }
  }
  float carry[16], aprod[16];
#pragma unroll
  for(int n=0;n<16;n++){ carry[n]=0.f; aprod[n]=1.f; }
  __syncthreads();
#pragma unroll 2
  for(int li=0; li<CHL; li++){
    int l = l0 + li;
    float d  = delta[l*DI+e];
    float xv = bf2f(*(const unsigned short*)&xs[l*DI+e]);
    float dxv = d*xv;
    const float4* bp = (const float4*)&bcs[li*32];
    float4 b0=bp[0], b1=bp[1], b2=bp[2], b3=bp[3];
    float B[16] = {b0.x,b0.y,b0.z,b0.w, b1.x,b1.y,b1.z,b1.w,
                   b2.x,b2.y,b2.z,b2.w, b3.x,b3.y,b3.z,b3.w};
#pragma unroll
    for(int n=0;n<16;n++){
      float dA = __expf(d*A[n]);
      carry[n] = fmaf(carry[n], dA, dxv*B[n]);
      aprod[n] *= dA;
    }
  }
  float4* ap = (float4*)&Atot[chunk*8192 + e*DS];
  float4* bp = (float4*)&Btot[chunk*8192 + e*DS];
#pragma unroll
  for(int q=0;q<4;q++){
    ap[q] = make_float4(aprod[q*4],aprod[q*4+1],aprod[q*4+2],aprod[q*4+3]);
    bp[q] = make_float4(carry[q*4],carry[q*4+1],carry[q*4+2],carry[q*4+3]);
  }
}

// ---- scan phase 2: carry-in per chunk (h0 may alias Btot: load-before-store) ----
__global__ void k_scan2(const float* __restrict__ Atot, const float* __restrict__ Btot,
                        float* __restrict__ h0){
  int tg = blockIdx.x*256 + threadIdx.x;
  float carry = 0.f;
  for(int c=0;c<NCH;c++){
    float a = Atot[c*8192+tg];
    float b = Btot[c*8192+tg];
    h0[c*8192+tg] = carry;
    carry = fmaf(carry, a, b);
  }
}

// ---- scan phase 3 (thread-per-channel): replay with carry-in,
//      fuse y = (sum_n h*C + xs*D) * silu(z), output bf16 ----
__global__ __launch_bounds__(256) void k_scan3(const float* __restrict__ delta,
                        const __hip_bfloat16* __restrict__ xs,
                        const float* __restrict__ dbc32, const float* __restrict__ A_log,
                        const float* __restrict__ Dp, const float* __restrict__ h0,
                        const __hip_bfloat16* __restrict__ xz, __hip_bfloat16* __restrict__ y){
  __shared__ float bcs[CHL*32];   // 4KB
  int t = threadIdx.x;
  int chunk = blockIdx.x >> 1;
  int e = ((blockIdx.x & 1) << 8) + t;
  int l0 = chunk*CHL;
  ((float4*)bcs)[t] = ((const float4*)&dbc32[l0*32])[t];
  float A[16];
  {
    const float4* al = (const float4*)&A_log[e*DS];
#pragma unroll
    for(int q=0;q<4;q++){
      float4 a = al[q];
      A[q*4+0] = -__expf(a.x); A[q*4+1] = -__expf(a.y);
      A[q*4+2] = -__expf(a.z); A[q*4+3] = -__expf(a.w);
    }
  }
  float carry[16];
  {
    const float4* hp = (const float4*)&h0[chunk*8192 + e*DS];
#pragma unroll
    for(int q=0;q<4;q++){
      float4 h = hp[q];
      carry[q*4+0]=h.x; carry[q*4+1]=h.y; carry[q*4+2]=h.z; carry[q*4+3]=h.w;
    }
  }
  float Dv = Dp[e];
  __syncthreads();
#pragma unroll 2
  for(int li=0; li<CHL; li++){
    int l = l0 + li;
    float d  = delta[l*DI+e];
    float xv = bf2f(*(const unsigned short*)&xs[l*DI+e]);
    float dxv = d*xv;
    const float4* bp = (const float4*)&bcs[li*32];
    float4 b0=bp[0], b1=bp[1], b2=bp[2], b3=bp[3];
    float4 c0=bp[4], c1=bp[5], c2=bp[6], c3=bp[7];
    float B[16] = {b0.x,b0.y,b0.z,b0.w, b1.x,b1.y,b1.z,b1.w,
                   b2.x,b2.y,b2.z,b2.w, b3.x,b3.y,b3.z,b3.w};
    float Cv[16] = {c0.x,c0.y,c0.z,c0.w, c1.x,c1.y,c1.z,c1.w,
                    c2.x,c2.y,c2.z,c2.w, c3.x,c3.y,c3.z,c3.w};
    float p[4] = {0.f,0.f,0.f,0.f};
#pragma unroll
    for(int n=0;n<16;n++){
      float dA = __expf(d*A[n]);
      carry[n] = fmaf(carry[n], dA, dxv*B[n]);
      p[n&3] = fmaf(carry[n], Cv[n], p[n&3]);
    }
    float ps = (p[0]+p[1]) + (p[2]+p[3]);
    float z = bf2f(*(const unsigned short*)&xz[l*1024 + 512 + e]);
    y[l*DI+e] = __float2bfloat16(fmaf(xv, Dv, ps) * silu_f(z));
  }
}

// ---- final: LN(128) -> @W2(128,1)+b2 -> tanh, one wave per row ----
__global__ void k_final(const float* __restrict__ h2, const float* __restrict__ g,
                        const float* __restrict__ b, const float* __restrict__ W2,
                        const float* __restrict__ b2, float* __restrict__ out){
  int lane = threadIdx.x&63;
  int wv = threadIdx.x>>6;
  int r = blockIdx.x*4 + wv;
  float v0 = h2[r*128+lane], v1 = h2[r*128+64+lane];
  float s = v0+v1, sq = v0*v0+v1*v1;
#pragma unroll
  for(int o=32;o;o>>=1){ s += __shfl_xor(s,o); sq += __shfl_xor(sq,o); }
  float mean = s*(1.0f/128), var = sq*(1.0f/128) - mean*mean;
  float rs = rsqrtf(var+1e-5f);
  float n0 = (v0-mean)*rs*g[lane]+b[lane];
  float n1 = (v1-mean)*rs*g[lane+64]+b[lane+64];
  float d = n0*W2[lane] + n1*W2[lane+64];
#pragma unroll
  for(int o=32;o;o>>=1) d += __shfl_xor(d,o);
  if(lane==0) out[r] = tanhf(d + b2[0]);
}

extern "C" void kernel_launch(void* const* d_in, const int* in_sizes, int n_in,
                              void* d_out, int out_size, void* d_ws, size_t ws_size,
                              hipStream_t stream){
  const float* x    = (const float*)d_in[0];
  const float* Win  = (const float*)d_in[1];
  const float* bin  = (const float*)d_in[2];
  const float* ln1g = (const float*)d_in[3];
  const float* ln1b = (const float*)d_in[4];
  const float* rmsw = (const float*)d_in[5];
  const float* inW  = (const float*)d_in[6];
  const float* convW= (const float*)d_in[7];
  const float* convB= (const float*)d_in[8];
  const float* xpW  = (const float*)d_in[9];
  const float* dtW  = (const float*)d_in[10];
  const float* dtB  = (const float*)d_in[11];
  const float* A_log= (const float*)d_in[12];
  const float* Dp   = (const float*)d_in[13];
  const float* outW = (const float*)d_in[14];
  const float* ln2g = (const float*)d_in[15];
  const float* ln2b = (const float*)d_in[16];
  const float* W1   = (const float*)d_in[17];
  const float* b1   = (const float*)d_in[18];
  const float* ln3g = (const float*)d_in[19];
  const float* ln3b = (const float*)d_in[20];
  const float* W2   = (const float*)d_in[21];
  const float* b2   = (const float*)d_in[22];
  float* out = (float*)d_out;
  float* ws = (float*)d_ws;
  float* u     = ws;                                          // 16384*256 f32
  __hip_bfloat16* hn_bf = (__hip_bfloat16*)(ws + 4194304);    // 16384*256 bf16
  __hip_bfloat16* xz_bf = (__hip_bfloat16*)(ws + 8388608);    // 16384*1024 bf16
  float* dbc32 = ws + 16777216;                               // 16384*32 f32
  float* delta = ws + 17301504;                               // 16384*512 f32
  __hip_bfloat16* y_bf  = (__hip_bfloat16*)(ws + 25690112);   // 16384*512 bf16
  __hip_bfloat16* xs_bf = (__hip_bfloat16*)(ws + 29884416);   // 16384*512 bf16
  float* Atot  = ws + 34078720;                               // NCH*8192 = 4194304
  float* Btot  = ws + 38273024;                               // NCH*8192 = 4194304
  float* h0    = Btot;                  // aliased (scan2 loads before store)
  float* h2    = u;                     // aliased (u dead after k_ln)
  __hip_bfloat16* inWt  = (__hip_bfloat16*)(ws + 42467328);   // 2*1024*256 bf16
  __hip_bfloat16* outWt = (__hip_bfloat16*)(ws + 42729472);   // 2*256*512 bf16
  __hip_bfloat16* W1t   = (__hip_bfloat16*)(ws + 42860544);   // 128*256 bf16
  __hip_bfloat16* Wd_t  = (__hip_bfloat16*)(ws + 42876928);   // 2*512*512 bf16
  __hip_bfloat16* Wbc_t = (__hip_bfloat16*)(ws + 43139072);   // 2*128*512 bf16

  k_cvtw<<<3200,256,0,stream>>>(inW, outW, W1, inWt, outWt, W1t);
  k_wd<<<2560,256,0,stream>>>(xpW, dtW, Wd_t, Wbc_t);
  k_input<<<L_SEQ,256,0,stream>>>(x,Win,bin,ln1g,ln1b,u);
  for(int i=0;i<2;i++){
    k_rms<<<L_SEQ,256,0,stream>>>(u, rmsw+i*DM, hn_bf);
    k_mgemm<0,__hip_bfloat16><<<dim3(8, L_SEQ/128),256,0,stream>>>(hn_bf, inWt+i*262144, nullptr, nullptr, xz_bf, L_SEQ, DM, 1024, 1024);
    k_conv<<<(L_SEQ/CLB)*128/256,256,0,stream>>>(xz_bf, convW+i*DI*4, convB+i*DI, xs_bf);
    k_mgemm<3,float><<<dim3(4, L_SEQ/128),256,0,stream>>>(xs_bf, Wd_t+i*262144, dtB+i*DI, nullptr, delta, L_SEQ, DI, 512, 512);
    k_mgemm<0,float><<<dim3(1, L_SEQ/128),256,0,stream>>>(xs_bf, Wbc_t+i*65536, nullptr, nullptr, dbc32, L_SEQ, DI, 32, 32);
    k_scan1<<<NCH*2,256,0,stream>>>(delta, xs_bf, dbc32, A_log+i*DI*DS, Atot, Btot);
    k_scan2<<<32,256,0,stream>>>(Atot, Btot, h0);
    k_scan3<<<NCH*2,256,0,stream>>>(delta, xs_bf, dbc32, A_log+i*DI*DS, Dp+i*DI, h0, xz_bf, y_bf);
    k_mgemm<1,float><<<dim3(2, L_SEQ/128),256,0,stream>>>(y_bf, outWt+i*131072, nullptr, u, u, L_SEQ, DI, 256, 256);
  }
  k_ln<<<L_SEQ,256,0,stream>>>(u, ln2g, ln2b, hn_bf);
  k_mgemm<2,float><<<dim3(1, L_SEQ/128),256,0,stream>>>(hn_bf, W1t, b1, nullptr, h2, L_SEQ, DM, 128, 128);
  k_final<<<L_SEQ/4,256,0,stream>>>(h2, ln3g, ln3b, W2, b2, out);
}